// Round 2
// baseline (158.183 us; speedup 1.0000x reference)
//
#include <hip/hip_runtime.h>

typedef __bf16 v8bf __attribute__((ext_vector_type(8)));
typedef __bf16 v4bf __attribute__((ext_vector_type(4)));
typedef __bf16 v2bf __attribute__((ext_vector_type(2)));
typedef float  v4f  __attribute__((ext_vector_type(4)));

namespace {

constexpr int kB = 512, kM = 4096, kH = 8;

// ws layout (bytes): wq 32KB @ 0, wk 32KB @ 32768, wfc 64KB @ 65536
// Tile swizzle: element (r, c) of a row-major [R x C] matrix lives at
//   tile = (r>>4)*(C/32) + (c>>5);  addr = tile*512 + (r&15)*32 + (c&31)

// ---------------- K0: weight casts + swizzle (1/64 folded into Wq) ----------------
__global__ __launch_bounds__(256) void k0_weights(
    const float* __restrict__ Wq, const float* __restrict__ Wk,
    const float* __restrict__ Wfc,
    __bf16* __restrict__ wq, __bf16* __restrict__ wk, __bf16* __restrict__ wfc) {
  int i = blockIdx.x * 256 + threadIdx.x;
  if (i < 16384) {
    int e = i >> 6, k = i & 63;
    int dst = ((e >> 4) * 2 + (k >> 5)) * 512 + (e & 15) * 32 + (k & 31);
    wq[dst] = (__bf16)(Wq[i] * 0.015625f);
  } else if (i < 32768) {
    int j = i - 16384;
    int e = j >> 6, k = j & 63;
    int dst = ((e >> 4) * 2 + (k >> 5)) * 512 + (e & 15) * 32 + (k & 31);
    wk[dst] = (__bf16)Wk[j];
  } else {
    int j = i - 32768;
    int o = j >> 9, f = j & 511;
    int dst = ((o >> 4) * 16 + (f >> 5)) * 512 + (o & 15) * 32 + (f & 31);
    wfc[dst] = (__bf16)Wfc[j];
  }
}

// ---------------- K1: fused per-b mega kernel, 2 head-streams in flight ----------------
// 512 threads = 8 waves: waves 0-3 = stream 0 (even heads), waves 4-7 = stream 1 (odd).
// LDS 73,760 B -> 2 blocks/CU -> 16 waves/CU. Head loop: 4 iterations, 3 barriers each.
__global__ __launch_bounds__(512, 4) void k_fused(
    const float* __restrict__ feat, const int* __restrict__ sidx,
    const float* __restrict__ gamma, const float* __restrict__ beta,
    const __bf16* __restrict__ wq, const __bf16* __restrict__ wk,
    const float* __restrict__ Wv1, const float* __restrict__ Wv2,
    const __bf16* __restrict__ wfc, float* __restrict__ out) {
  __shared__ __align__(16) __bf16 smem[36864];
  __shared__ float red[8];
  __bf16* s_feat = smem;           // 4096   raw features bf16 (shared, both streams)
  __bf16* s_qin  = smem + 4096;    // 4096   LN output, tile-swizzled (shared)
  __bf16* sb     = smem + 8192 + (threadIdx.x >> 8) * 14336;  // per-stream arena
  __bf16* s_kf   = sb;             // 64x72  gathered kf; aliased as scores + o-tile later
  __bf16* s_q    = sb + 4608;      // 64x40  (wave-private rows)
  __bf16* s_K    = sb + 7168;      // 64x40
  __bf16* s_vT   = sb + 9728;      // 64x72  v^T [s][n]
  __bf16* s_sc   = s_kf;           // alias: s_kf dead once scores start

  const int b = blockIdx.x;
  const int t = threadIdx.x;
  const int stream = t >> 8, ts = t & 255;          // 256 threads per stream
  const int w = t >> 6, w4 = w & 3, lane = t & 63;  // w4 = wave within stream
  const int quad = lane >> 4, l16 = lane & 15;

  // ---- LN phase (+ prefetch head {stream} gather indices) ----
  const float4* frow4 = reinterpret_cast<const float4*>(feat + (size_t)b * kM);
  const float4* g4  = reinterpret_cast<const float4*>(gamma);
  const float4* be4 = reinterpret_cast<const float4*>(beta);
  float4 xs[2];
  float s = 0.f;
#pragma unroll
  for (int j = 0; j < 2; ++j) {
    xs[j] = frow4[t + j * 512];
    s += xs[j].x + xs[j].y + xs[j].z + xs[j].w;
  }
  int idxr[16], idxn[16];
#pragma unroll
  for (int j = 0; j < 16; ++j) idxr[j] = sidx[stream * kM + ts + j * 256];
#pragma unroll
  for (int o = 32; o > 0; o >>= 1) s += __shfl_xor(s, o);
  if (lane == 0) red[w] = s;
  __syncthreads();
  const float mu = (red[0] + red[1] + red[2] + red[3] +
                    red[4] + red[5] + red[6] + red[7]) * (1.f / kM);
  float var_p = 0.f;
#pragma unroll
  for (int j = 0; j < 2; ++j) {
    float d0 = xs[j].x - mu, d1 = xs[j].y - mu, d2 = xs[j].z - mu, d3 = xs[j].w - mu;
    var_p += d0 * d0 + d1 * d1 + d2 * d2 + d3 * d3;
  }
#pragma unroll
  for (int o = 32; o > 0; o >>= 1) var_p += __shfl_xor(var_p, o);
  __syncthreads();
  if (lane == 0) red[w] = var_p;
  __syncthreads();
  const float var  = (red[0] + red[1] + red[2] + red[3] +
                      red[4] + red[5] + red[6] + red[7]) * (1.f / kM);
  const float rstd = rsqrtf(var + 1e-5f);
#pragma unroll
  for (int j = 0; j < 2; ++j) {
    const int i4 = t + j * 512;
    float4 g = g4[i4], bt = be4[i4];
    v4bf fb, qb;
    fb[0] = (__bf16)xs[j].x; fb[1] = (__bf16)xs[j].y;
    fb[2] = (__bf16)xs[j].z; fb[3] = (__bf16)xs[j].w;
    qb[0] = (__bf16)((xs[j].x - mu) * rstd * g.x + bt.x);
    qb[1] = (__bf16)((xs[j].y - mu) * rstd * g.y + bt.y);
    qb[2] = (__bf16)((xs[j].z - mu) * rstd * g.z + bt.z);
    qb[3] = (__bf16)((xs[j].w - mu) * rstd * g.w + bt.w);
    *(v4bf*)(s_feat + 4 * i4) = fb;
    // element m = 4*i4 + c -> n = i4>>4, k = 4*(t&15) + c
    const int n = i4 >> 4, k = 4 * (t & 15);
    const int dst = ((n >> 4) * 2 + (k >> 5)) * 512 + (n & 15) * 32 + (k & 31);
    *(v4bf*)(s_qin + dst) = qb;
  }
  if (ts < 64) { v8bf z = {}; *(v8bf*)(s_kf + ts * 72 + 64) = z; }  // conv pad, both streams
  __syncthreads();  // bar0: s_feat, s_qin ready

  v4f acc[4] = {{0.f, 0.f, 0.f, 0.f}, {0.f, 0.f, 0.f, 0.f},
                {0.f, 0.f, 0.f, 0.f}, {0.f, 0.f, 0.f, 0.f}};  // fc accumulator (per stream)

  for (int it = 0; it < 4; ++it) {
    const int h = 2 * it + stream;

    // ---- q-GEMM (s_qin shared read-only + wq global; s_q rows wave-private)
    {
      v4f dq0 = {0.f, 0.f, 0.f, 0.f}, dq1 = {0.f, 0.f, 0.f, 0.f};
#pragma unroll
      for (int kt = 0; kt < 2; ++kt) {
        v8bf a  = *(const v8bf*)(s_qin + (2 * w4 + kt) * 512 + l16 * 32 + 8 * quad);
        v8bf b0 = *(const v8bf*)(wq + (size_t)(4 * h + kt) * 512 + l16 * 32 + 8 * quad);
        v8bf b1 = *(const v8bf*)(wq + (size_t)(4 * h + 2 + kt) * 512 + l16 * 32 + 8 * quad);
        dq0 = __builtin_amdgcn_mfma_f32_16x16x32_bf16(a, b0, dq0, 0, 0, 0);
        dq1 = __builtin_amdgcn_mfma_f32_16x16x32_bf16(a, b1, dq1, 0, 0, 0);
      }
#pragma unroll
      for (int r = 0; r < 4; ++r) {
        s_q[(16 * w4 + 4 * quad + r) * 40 + l16]      = (__bf16)dq0[r];
        s_q[(16 * w4 + 4 * quad + r) * 40 + 16 + l16] = (__bf16)dq1[r];
      }
    }

    // ---- prefetch next head's gather indices (overlaps everything below)
    if (it < 3) {
      const int* idxp = sidx + (size_t)(h + 2) * kM;
#pragma unroll
      for (int j = 0; j < 16; ++j) idxn[j] = idxp[ts + j * 256];
    }

    // ---- gather kf from LDS (random b16 reads on the crossbar)
#pragma unroll
    for (int j = 0; j < 16; ++j) {
      int i = ts + j * 256;
      s_kf[(i >> 6) * 72 + (i & 63)] = s_feat[idxr[j]];
    }
    __syncthreads();  // bar1: s_kf ready (both streams)

    // ---- K-GEMM
    {
      v4f dk0 = {0.f, 0.f, 0.f, 0.f}, dk1 = {0.f, 0.f, 0.f, 0.f};
#pragma unroll
      for (int kt = 0; kt < 2; ++kt) {
        v8bf a  = *(const v8bf*)(s_kf + (16 * w4 + l16) * 72 + 32 * kt + 8 * quad);
        v8bf b0 = *(const v8bf*)(wk + (size_t)(4 * h + kt) * 512 + l16 * 32 + 8 * quad);
        v8bf b1 = *(const v8bf*)(wk + (size_t)(4 * h + 2 + kt) * 512 + l16 * 32 + 8 * quad);
        dk0 = __builtin_amdgcn_mfma_f32_16x16x32_bf16(a, b0, dk0, 0, 0, 0);
        dk1 = __builtin_amdgcn_mfma_f32_16x16x32_bf16(a, b1, dk1, 0, 0, 0);
      }
#pragma unroll
      for (int r = 0; r < 4; ++r) {
        s_K[(16 * w4 + 4 * quad + r) * 40 + l16]      = (__bf16)dk0[r];
        s_K[(16 * w4 + 4 * quad + r) * 40 + 16 + l16] = (__bf16)dk1[r];
      }
    }

    // ---- windowed conv + relu + residual, written transposed (v^T[s][n])
    {
      const int n = lane, p0 = w4 * 16;
      float w1[4][3], w2[4];
#pragma unroll
      for (int d = 0; d < 4; ++d) {
#pragma unroll
        for (int c = 0; c < 3; ++c) w1[d][c] = Wv1[(h * 4 + d) * 3 + c];
        w2[d] = Wv2[h * 4 + d];
      }
      v8bf xa = *(const v8bf*)(s_kf + n * 72 + p0);
      v8bf xb = *(const v8bf*)(s_kf + n * 72 + p0 + 8);
      v2bf xc = *(const v2bf*)(s_kf + n * 72 + p0 + 16);  // pad cols zeroed
      float x[18];
#pragma unroll
      for (int c = 0; c < 8; ++c) { x[c] = (float)xa[c]; x[c + 8] = (float)xb[c]; }
      x[16] = (float)xc[0]; x[17] = (float)xc[1];
#pragma unroll
      for (int pp = 0; pp < 16; ++pp) {
        float a0 = x[pp];
#pragma unroll
        for (int d = 0; d < 4; ++d) {
          float v1 = fmaf(x[pp + 2], w1[d][2], fmaf(x[pp + 1], w1[d][1], x[pp] * w1[d][0]));
          a0 = fmaf(fmaxf(v1, 0.f), w2[d], a0);
        }
        s_vT[(p0 + pp) * 72 + n] = (__bf16)a0;
      }
    }
    __syncthreads();  // bar2: s_K, s_vT ready; all s_kf readers done (s_sc alias safe)

    // ---- scores[qi][n] = q[qi][d] * K[n][d]
    {
      v4f ds[4] = {{0.f, 0.f, 0.f, 0.f}, {0.f, 0.f, 0.f, 0.f},
                   {0.f, 0.f, 0.f, 0.f}, {0.f, 0.f, 0.f, 0.f}};
      v8bf a = *(const v8bf*)(s_q + (16 * w4 + l16) * 40 + 8 * quad);
#pragma unroll
      for (int nt = 0; nt < 4; ++nt) {
        v8bf bb = *(const v8bf*)(s_K + (16 * nt + l16) * 40 + 8 * quad);
        ds[nt] = __builtin_amdgcn_mfma_f32_16x16x32_bf16(a, bb, ds[nt], 0, 0, 0);
      }
#pragma unroll
      for (int nt = 0; nt < 4; ++nt)
#pragma unroll
        for (int r = 0; r < 4; ++r)
          s_sc[(16 * w4 + 4 * quad + r) * 72 + 16 * nt + l16] = (__bf16)ds[nt][r];
    }
    // no barrier: wave w4 owns rows 16w4..16w4+15 of s_sc end-to-end

    // ---- softmax + attn output
    float* attn_out = out + (size_t)kB * kM + ((size_t)(b * kH + h)) * 4096;
#pragma unroll
    for (int rr = 0; rr < 4; ++rr) {
      const int row = 16 * w4 + 4 * rr + quad;
      v4bf pv = *(const v4bf*)(s_sc + row * 72 + 4 * l16);
      float e0 = (float)pv[0], e1 = (float)pv[1], e2 = (float)pv[2], e3 = (float)pv[3];
      float mx = fmaxf(fmaxf(e0, e1), fmaxf(e2, e3));
#pragma unroll
      for (int mk = 8; mk > 0; mk >>= 1) mx = fmaxf(mx, __shfl_xor(mx, mk));
      e0 = __expf(e0 - mx); e1 = __expf(e1 - mx);
      e2 = __expf(e2 - mx); e3 = __expf(e3 - mx);
      float ssum = e0 + e1 + e2 + e3;
#pragma unroll
      for (int mk = 8; mk > 0; mk >>= 1) ssum += __shfl_xor(ssum, mk);
      const float inv = 1.0f / ssum;
      e0 *= inv; e1 *= inv; e2 *= inv; e3 *= inv;
      *(float4*)(attn_out + row * 64 + 4 * l16) = make_float4(e0, e1, e2, e3);
      v4bf st;
      st[0] = (__bf16)e0; st[1] = (__bf16)e1; st[2] = (__bf16)e2; st[3] = (__bf16)e3;
      *(v4bf*)(s_sc + row * 72 + 4 * l16) = st;
    }

    // ---- PV: o[qi][s] = attn[qi][n] * vT[s][n]
    v4f dO[4] = {{0.f, 0.f, 0.f, 0.f}, {0.f, 0.f, 0.f, 0.f},
                 {0.f, 0.f, 0.f, 0.f}, {0.f, 0.f, 0.f, 0.f}};
#pragma unroll
    for (int kt = 0; kt < 2; ++kt) {
      v8bf a = *(const v8bf*)(s_sc + (16 * w4 + l16) * 72 + 32 * kt + 8 * quad);
#pragma unroll
      for (int st = 0; st < 4; ++st) {
        v8bf bb = *(const v8bf*)(s_vT + (16 * st + l16) * 72 + 32 * kt + 8 * quad);
        dO[st] = __builtin_amdgcn_mfma_f32_16x16x32_bf16(a, bb, dO[st], 0, 0, 0);
      }
    }

    // ---- fc partial: acc[n][o] += o_h[n][k] * Wfc[o][h*64+k]
    // o round-trips through the wave's own dead s_sc slice (16 rows x 72 >= 1024 elems).
    {
      __bf16* ob = s_kf + w4 * 1152;  // wave-private: rows 16*w4..16*w4+15
#pragma unroll
      for (int st = 0; st < 4; ++st)
#pragma unroll
        for (int r = 0; r < 4; ++r)
          ob[(st >> 1) * 512 + (4 * quad + r) * 32 + (st & 1) * 16 + l16] = (__bf16)dO[st][r];
#pragma unroll
      for (int kt = 0; kt < 2; ++kt) {
        v8bf a = *(const v8bf*)(ob + kt * 512 + l16 * 32 + 8 * quad);
#pragma unroll
        for (int nt = 0; nt < 4; ++nt) {
          v8bf bb = *(const v8bf*)(wfc + (size_t)(nt * 16 + h * 2 + kt) * 512 + l16 * 32 + 8 * quad);
          acc[nt] = __builtin_amdgcn_mfma_f32_16x16x32_bf16(a, bb, acc[nt], 0, 0, 0);
        }
      }
    }
    __syncthreads();  // bar3: all cross-wave reads done before next head's writes

    if (it < 3) {
#pragma unroll
      for (int j = 0; j < 16; ++j) idxr[j] = idxn[j];
    }
  }

  // ---- combine fc partials across streams, write out[b*4096 + n*64 + o]
  float* accf = (float*)smem;  // 64 x 65 fp32 (16.6 KB) over dead s_feat/s_qin/s_kf0
  if (stream == 0) {
#pragma unroll
    for (int nt = 0; nt < 4; ++nt)
#pragma unroll
      for (int r = 0; r < 4; ++r)
        accf[(16 * w4 + 4 * quad + r) * 65 + 16 * nt + l16] = acc[nt][r];
  }
  __syncthreads();
  if (stream == 1) {
    float* orow = out + (size_t)b * kM;
#pragma unroll
    for (int nt = 0; nt < 4; ++nt)
#pragma unroll
      for (int r = 0; r < 4; ++r) {
        const int row = 16 * w4 + 4 * quad + r, col = 16 * nt + l16;
        orow[row * 64 + col] = acc[nt][r] + accf[row * 65 + col];
      }
  }
}

}  // namespace

extern "C" void kernel_launch(void* const* d_in, const int* in_sizes, int n_in,
                              void* d_out, int out_size, void* d_ws, size_t ws_size,
                              hipStream_t stream) {
  (void)in_sizes; (void)n_in; (void)out_size; (void)ws_size;
  const float* features = (const float*)d_in[0];
  const int*   sidx     = (const int*)d_in[1];
  const float* gamma    = (const float*)d_in[2];
  const float* beta     = (const float*)d_in[3];
  const float* Wq       = (const float*)d_in[4];
  const float* Wk       = (const float*)d_in[5];
  const float* Wv1      = (const float*)d_in[6];
  const float* Wv2      = (const float*)d_in[7];
  const float* Wfc      = (const float*)d_in[8];
  float* out = (float*)d_out;

  char* ws = (char*)d_ws;
  __bf16* ws_wq  = (__bf16*)(ws);
  __bf16* ws_wk  = (__bf16*)(ws + 32768);
  __bf16* ws_wfc = (__bf16*)(ws + 65536);

  hipLaunchKernelGGL(k0_weights, dim3(256), dim3(256), 0, stream,
                     Wq, Wk, Wfc, ws_wq, ws_wk, ws_wfc);
  hipLaunchKernelGGL(k_fused, dim3(kB), dim3(512), 0, stream,
                     features, sidx, gamma, beta, ws_wq, ws_wk, Wv1, Wv2, ws_wfc, out);
}

// Round 3
// 154.650 us; speedup vs baseline: 1.0228x; 1.0228x over previous
//
#include <hip/hip_runtime.h>

typedef __bf16 v8bf __attribute__((ext_vector_type(8)));
typedef __bf16 v4bf __attribute__((ext_vector_type(4)));
typedef __bf16 v2bf __attribute__((ext_vector_type(2)));
typedef float  v4f  __attribute__((ext_vector_type(4)));

namespace {

constexpr int kB = 512, kM = 4096, kH = 8;

// ws layout (bytes): wq 32KB @ 0, wk 32KB @ 32768, wfc 64KB @ 65536
// Tile swizzle: element (r, c) of a row-major [R x C] matrix lives at
//   tile = (r>>4)*(C/32) + (c>>5);  addr = tile*512 + (r&15)*32 + (c&31)

// ---------------- K0: weight casts + swizzle + zero-init of fc out region ----------------
// grid 2048 x 256 = 524288 threads: every thread zeroes one float4 of out[0 : 512*4096);
// threads < 65536 also cast/swizzle one weight element. Idempotent across graph replays.
__global__ __launch_bounds__(256) void k0_weights(
    const float* __restrict__ Wq, const float* __restrict__ Wk,
    const float* __restrict__ Wfc,
    __bf16* __restrict__ wq, __bf16* __restrict__ wk, __bf16* __restrict__ wfc,
    float* __restrict__ out) {
  int i = blockIdx.x * 256 + threadIdx.x;
  reinterpret_cast<float4*>(out)[i] = make_float4(0.f, 0.f, 0.f, 0.f);
  if (i < 16384) {
    int e = i >> 6, k = i & 63;
    int dst = ((e >> 4) * 2 + (k >> 5)) * 512 + (e & 15) * 32 + (k & 31);
    wq[dst] = (__bf16)(Wq[i] * 0.015625f);
  } else if (i < 32768) {
    int j = i - 16384;
    int e = j >> 6, k = j & 63;
    int dst = ((e >> 4) * 2 + (k >> 5)) * 512 + (e & 15) * 32 + (k & 31);
    wk[dst] = (__bf16)Wk[j];
  } else if (i < 65536) {
    int j = i - 32768;
    int o = j >> 9, f = j & 511;
    int dst = ((o >> 4) * 16 + (f >> 5)) * 512 + (o & 15) * 32 + (f & 31);
    wfc[dst] = (__bf16)Wfc[j];
  }
}

// ---------------- K1: fused kernel, 4 heads per block, 2 blocks per b ----------------
// grid (512, 2): block (b, half) does heads [4*half, 4*half+4). 256 threads, LDS 45 KB
// -> 3 blocks/CU resident (12 waves/CU). fc partials combined via fp32 atomicAdd
// into the k0-zeroed out region.
__global__ __launch_bounds__(256, 3) void k_fused(
    const float* __restrict__ feat, const int* __restrict__ sidx,
    const float* __restrict__ gamma, const float* __restrict__ beta,
    const __bf16* __restrict__ wq, const __bf16* __restrict__ wk,
    const float* __restrict__ Wv1, const float* __restrict__ Wv2,
    const __bf16* __restrict__ wfc, float* __restrict__ out) {
  __shared__ __align__(16) __bf16 smem[22528];  // 45,056 B
  __shared__ float red[4];
  __bf16* s_feat = smem;           // 4096   raw features bf16 (gather source, all heads)
  __bf16* s_qin  = smem + 4096;    // 4096   LN output, tile-swizzled (all heads)
  __bf16* s_kf   = smem + 8192;    // 64x72  gathered kf; aliased as scores + fc staging
  __bf16* s_q    = smem + 12800;   // 64x40  (wave-private rows)
  __bf16* s_K    = smem + 15360;   // 64x40
  __bf16* s_vT   = smem + 17920;   // 64x72  v^T [s][n]
  __bf16* s_sc   = s_kf;           // alias: s_kf dead once scores start

  const int b = blockIdx.x, half = blockIdx.y, h0 = 4 * half;
  const int t = threadIdx.x, w = t >> 6, lane = t & 63;
  const int quad = lane >> 4, l16 = lane & 15;

  // ---- LN phase (+ prefetch first head's gather indices) ----
  const float4* frow4 = reinterpret_cast<const float4*>(feat + (size_t)b * kM);
  const float4* g4  = reinterpret_cast<const float4*>(gamma);
  const float4* be4 = reinterpret_cast<const float4*>(beta);
  float4 xs[4];
  float s = 0.f;
#pragma unroll
  for (int j = 0; j < 4; ++j) {
    xs[j] = frow4[t + j * 256];
    s += xs[j].x + xs[j].y + xs[j].z + xs[j].w;
  }
  int idxr[16], idxn[16];
#pragma unroll
  for (int j = 0; j < 16; ++j) idxr[j] = sidx[(size_t)h0 * kM + t + j * 256];
#pragma unroll
  for (int o = 32; o > 0; o >>= 1) s += __shfl_xor(s, o);
  if (lane == 0) red[w] = s;
  __syncthreads();
  const float mu = (red[0] + red[1] + red[2] + red[3]) * (1.f / kM);
  float var_p = 0.f;
#pragma unroll
  for (int j = 0; j < 4; ++j) {
    float d0 = xs[j].x - mu, d1 = xs[j].y - mu, d2 = xs[j].z - mu, d3 = xs[j].w - mu;
    var_p += d0 * d0 + d1 * d1 + d2 * d2 + d3 * d3;
  }
#pragma unroll
  for (int o = 32; o > 0; o >>= 1) var_p += __shfl_xor(var_p, o);
  __syncthreads();
  if (lane == 0) red[w] = var_p;
  __syncthreads();
  const float var  = (red[0] + red[1] + red[2] + red[3]) * (1.f / kM);
  const float rstd = rsqrtf(var + 1e-5f);
#pragma unroll
  for (int j = 0; j < 4; ++j) {
    const int i4 = t + j * 256;
    float4 g = g4[i4], bt = be4[i4];
    v4bf fb, qb;
    fb[0] = (__bf16)xs[j].x; fb[1] = (__bf16)xs[j].y;
    fb[2] = (__bf16)xs[j].z; fb[3] = (__bf16)xs[j].w;
    qb[0] = (__bf16)((xs[j].x - mu) * rstd * g.x + bt.x);
    qb[1] = (__bf16)((xs[j].y - mu) * rstd * g.y + bt.y);
    qb[2] = (__bf16)((xs[j].z - mu) * rstd * g.z + bt.z);
    qb[3] = (__bf16)((xs[j].w - mu) * rstd * g.w + bt.w);
    *(v4bf*)(s_feat + 4 * i4) = fb;
    // element m = 4*i4 + c -> n = i4>>4, k = 4*(t&15) + c
    const int n = i4 >> 4, k = 4 * (t & 15);
    const int dst = ((n >> 4) * 2 + (k >> 5)) * 512 + (n & 15) * 32 + (k & 31);
    *(v4bf*)(s_qin + dst) = qb;
  }
  __syncthreads();  // bar0: s_feat, s_qin ready

  v4f acc[4] = {{0.f, 0.f, 0.f, 0.f}, {0.f, 0.f, 0.f, 0.f},
                {0.f, 0.f, 0.f, 0.f}, {0.f, 0.f, 0.f, 0.f}};  // fc partial (this half)

  for (int it = 0; it < 4; ++it) {
    const int h = h0 + it;

    // ---- q-GEMM (s_qin LDS + wq global; s_q rows wave-private)
    {
      v4f dq0 = {0.f, 0.f, 0.f, 0.f}, dq1 = {0.f, 0.f, 0.f, 0.f};
#pragma unroll
      for (int kt = 0; kt < 2; ++kt) {
        v8bf a  = *(const v8bf*)(s_qin + (2 * w + kt) * 512 + l16 * 32 + 8 * quad);
        v8bf b0 = *(const v8bf*)(wq + (size_t)(4 * h + kt) * 512 + l16 * 32 + 8 * quad);
        v8bf b1 = *(const v8bf*)(wq + (size_t)(4 * h + 2 + kt) * 512 + l16 * 32 + 8 * quad);
        dq0 = __builtin_amdgcn_mfma_f32_16x16x32_bf16(a, b0, dq0, 0, 0, 0);
        dq1 = __builtin_amdgcn_mfma_f32_16x16x32_bf16(a, b1, dq1, 0, 0, 0);
      }
#pragma unroll
      for (int r = 0; r < 4; ++r) {
        s_q[(16 * w + 4 * quad + r) * 40 + l16]      = (__bf16)dq0[r];
        s_q[(16 * w + 4 * quad + r) * 40 + 16 + l16] = (__bf16)dq1[r];
      }
    }

    // ---- prefetch next head's gather indices (overlaps everything below)
    if (it < 3) {
      const int* idxp = sidx + (size_t)(h + 1) * kM;
#pragma unroll
      for (int j = 0; j < 16; ++j) idxn[j] = idxp[t + j * 256];
    }

    // ---- gather kf from LDS (random b16 reads on the crossbar)
#pragma unroll
    for (int j = 0; j < 16; ++j) {
      int i = t + j * 256;
      s_kf[(i >> 6) * 72 + (i & 63)] = s_feat[idxr[j]];
    }
    // re-zero conv pad cols 64..71 every iteration (fc staging clobbers them)
    if (t < 64) { v8bf z = {}; *(v8bf*)(s_kf + t * 72 + 64) = z; }
    __syncthreads();  // bar1: s_kf ready

    // ---- K-GEMM
    {
      v4f dk0 = {0.f, 0.f, 0.f, 0.f}, dk1 = {0.f, 0.f, 0.f, 0.f};
#pragma unroll
      for (int kt = 0; kt < 2; ++kt) {
        v8bf a  = *(const v8bf*)(s_kf + (16 * w + l16) * 72 + 32 * kt + 8 * quad);
        v8bf b0 = *(const v8bf*)(wk + (size_t)(4 * h + kt) * 512 + l16 * 32 + 8 * quad);
        v8bf b1 = *(const v8bf*)(wk + (size_t)(4 * h + 2 + kt) * 512 + l16 * 32 + 8 * quad);
        dk0 = __builtin_amdgcn_mfma_f32_16x16x32_bf16(a, b0, dk0, 0, 0, 0);
        dk1 = __builtin_amdgcn_mfma_f32_16x16x32_bf16(a, b1, dk1, 0, 0, 0);
      }
#pragma unroll
      for (int r = 0; r < 4; ++r) {
        s_K[(16 * w + 4 * quad + r) * 40 + l16]      = (__bf16)dk0[r];
        s_K[(16 * w + 4 * quad + r) * 40 + 16 + l16] = (__bf16)dk1[r];
      }
    }

    // ---- windowed conv + relu + residual, written transposed (v^T[s][n])
    {
      const int n = lane, p0 = w * 16;
      float w1[4][3], w2[4];
#pragma unroll
      for (int d = 0; d < 4; ++d) {
#pragma unroll
        for (int c = 0; c < 3; ++c) w1[d][c] = Wv1[(h * 4 + d) * 3 + c];
        w2[d] = Wv2[h * 4 + d];
      }
      v8bf xa = *(const v8bf*)(s_kf + n * 72 + p0);
      v8bf xb = *(const v8bf*)(s_kf + n * 72 + p0 + 8);
      v2bf xc = *(const v2bf*)(s_kf + n * 72 + p0 + 16);  // pad cols re-zeroed above
      float x[18];
#pragma unroll
      for (int c = 0; c < 8; ++c) { x[c] = (float)xa[c]; x[c + 8] = (float)xb[c]; }
      x[16] = (float)xc[0]; x[17] = (float)xc[1];
#pragma unroll
      for (int pp = 0; pp < 16; ++pp) {
        float a0 = x[pp];
#pragma unroll
        for (int d = 0; d < 4; ++d) {
          float v1 = fmaf(x[pp + 2], w1[d][2], fmaf(x[pp + 1], w1[d][1], x[pp] * w1[d][0]));
          a0 = fmaf(fmaxf(v1, 0.f), w2[d], a0);
        }
        s_vT[(p0 + pp) * 72 + n] = (__bf16)a0;
      }
    }
    __syncthreads();  // bar2: s_K, s_vT ready; all s_kf readers done (s_sc alias safe)

    // ---- scores[qi][n] = q[qi][d] * K[n][d]
    {
      v4f ds[4] = {{0.f, 0.f, 0.f, 0.f}, {0.f, 0.f, 0.f, 0.f},
                   {0.f, 0.f, 0.f, 0.f}, {0.f, 0.f, 0.f, 0.f}};
      v8bf a = *(const v8bf*)(s_q + (16 * w + l16) * 40 + 8 * quad);
#pragma unroll
      for (int nt = 0; nt < 4; ++nt) {
        v8bf bb = *(const v8bf*)(s_K + (16 * nt + l16) * 40 + 8 * quad);
        ds[nt] = __builtin_amdgcn_mfma_f32_16x16x32_bf16(a, bb, ds[nt], 0, 0, 0);
      }
#pragma unroll
      for (int nt = 0; nt < 4; ++nt)
#pragma unroll
        for (int r = 0; r < 4; ++r)
          s_sc[(16 * w + 4 * quad + r) * 72 + 16 * nt + l16] = (__bf16)ds[nt][r];
    }
    // no barrier: wave w owns rows 16w..16w+15 of s_sc end-to-end

    // ---- softmax + attn output
    float* attn_out = out + (size_t)kB * kM + ((size_t)(b * kH + h)) * 4096;
#pragma unroll
    for (int rr = 0; rr < 4; ++rr) {
      const int row = 16 * w + 4 * rr + quad;
      v4bf pv = *(const v4bf*)(s_sc + row * 72 + 4 * l16);
      float e0 = (float)pv[0], e1 = (float)pv[1], e2 = (float)pv[2], e3 = (float)pv[3];
      float mx = fmaxf(fmaxf(e0, e1), fmaxf(e2, e3));
#pragma unroll
      for (int mk = 8; mk > 0; mk >>= 1) mx = fmaxf(mx, __shfl_xor(mx, mk));
      e0 = __expf(e0 - mx); e1 = __expf(e1 - mx);
      e2 = __expf(e2 - mx); e3 = __expf(e3 - mx);
      float ssum = e0 + e1 + e2 + e3;
#pragma unroll
      for (int mk = 8; mk > 0; mk >>= 1) ssum += __shfl_xor(ssum, mk);
      const float inv = 1.0f / ssum;
      e0 *= inv; e1 *= inv; e2 *= inv; e3 *= inv;
      *(float4*)(attn_out + row * 64 + 4 * l16) = make_float4(e0, e1, e2, e3);
      v4bf st;
      st[0] = (__bf16)e0; st[1] = (__bf16)e1; st[2] = (__bf16)e2; st[3] = (__bf16)e3;
      *(v4bf*)(s_sc + row * 72 + 4 * l16) = st;
    }

    // ---- PV: o[qi][s] = attn[qi][n] * vT[s][n]
    v4f dO[4] = {{0.f, 0.f, 0.f, 0.f}, {0.f, 0.f, 0.f, 0.f},
                 {0.f, 0.f, 0.f, 0.f}, {0.f, 0.f, 0.f, 0.f}};
#pragma unroll
    for (int kt = 0; kt < 2; ++kt) {
      v8bf a = *(const v8bf*)(s_sc + (16 * w + l16) * 72 + 32 * kt + 8 * quad);
#pragma unroll
      for (int st = 0; st < 4; ++st) {
        v8bf bb = *(const v8bf*)(s_vT + (16 * st + l16) * 72 + 32 * kt + 8 * quad);
        dO[st] = __builtin_amdgcn_mfma_f32_16x16x32_bf16(a, bb, dO[st], 0, 0, 0);
      }
    }

    // ---- fc partial: acc[n][o] += o_h[n][k] * Wfc[o][h*64+k]
    // o round-trips through the wave's own dead s_sc slice (wave-private rows).
    {
      __bf16* ob = s_kf + w * 1152;  // rows 16w..16w+15 of s_sc (72-stride region)
#pragma unroll
      for (int st = 0; st < 4; ++st)
#pragma unroll
        for (int r = 0; r < 4; ++r)
          ob[(st >> 1) * 512 + (4 * quad + r) * 32 + (st & 1) * 16 + l16] = (__bf16)dO[st][r];
#pragma unroll
      for (int kt = 0; kt < 2; ++kt) {
        v8bf a = *(const v8bf*)(ob + kt * 512 + l16 * 32 + 8 * quad);
#pragma unroll
        for (int nt = 0; nt < 4; ++nt) {
          v8bf bb = *(const v8bf*)(wfc + (size_t)(nt * 16 + h * 2 + kt) * 512 + l16 * 32 + 8 * quad);
          acc[nt] = __builtin_amdgcn_mfma_f32_16x16x32_bf16(a, bb, acc[nt], 0, 0, 0);
        }
      }
    }
    __syncthreads();  // bar3: all cross-wave reads done before next head's writes

    if (it < 3) {
#pragma unroll
      for (int j = 0; j < 16; ++j) idxr[j] = idxn[j];
    }
  }

  // ---- combine fc partials across the two half-blocks via atomicAdd (out pre-zeroed by k0)
  float* orow = out + (size_t)b * kM;
#pragma unroll
  for (int nt = 0; nt < 4; ++nt)
#pragma unroll
    for (int r = 0; r < 4; ++r)
      atomicAdd(&orow[(16 * w + 4 * quad + r) * 64 + 16 * nt + l16], acc[nt][r]);
}

}  // namespace

extern "C" void kernel_launch(void* const* d_in, const int* in_sizes, int n_in,
                              void* d_out, int out_size, void* d_ws, size_t ws_size,
                              hipStream_t stream) {
  (void)in_sizes; (void)n_in; (void)out_size; (void)ws_size;
  const float* features = (const float*)d_in[0];
  const int*   sidx     = (const int*)d_in[1];
  const float* gamma    = (const float*)d_in[2];
  const float* beta     = (const float*)d_in[3];
  const float* Wq       = (const float*)d_in[4];
  const float* Wk       = (const float*)d_in[5];
  const float* Wv1      = (const float*)d_in[6];
  const float* Wv2      = (const float*)d_in[7];
  const float* Wfc      = (const float*)d_in[8];
  float* out = (float*)d_out;

  char* ws = (char*)d_ws;
  __bf16* ws_wq  = (__bf16*)(ws);
  __bf16* ws_wk  = (__bf16*)(ws + 32768);
  __bf16* ws_wfc = (__bf16*)(ws + 65536);

  hipLaunchKernelGGL(k0_weights, dim3(2048), dim3(256), 0, stream,
                     Wq, Wk, Wfc, ws_wq, ws_wk, ws_wfc, out);
  hipLaunchKernelGGL(k_fused, dim3(kB, 2), dim3(256), 0, stream,
                     features, sidx, gamma, beta, ws_wq, ws_wk, Wv1, Wv2, ws_wfc, out);
}

// Round 4
// 146.270 us; speedup vs baseline: 1.0814x; 1.0573x over previous
//
#include <hip/hip_runtime.h>

typedef __bf16 v8bf __attribute__((ext_vector_type(8)));
typedef __bf16 v4bf __attribute__((ext_vector_type(4)));
typedef __bf16 v2bf __attribute__((ext_vector_type(2)));
typedef float  v4f  __attribute__((ext_vector_type(4)));
typedef unsigned long long u64;

namespace {

constexpr int kB = 512, kM = 4096, kH = 8;

// ws layout (bytes): wq 32KB @ 0, wk 32KB @ 32768, wfc 64KB @ 65536
// Tile swizzle: element (r, c) of a row-major [R x C] matrix lives at
//   tile = (r>>4)*(C/32) + (c>>5);  addr = tile*512 + (r&15)*32 + (c&31)

// ---------------- K0: weight casts + swizzle + zero-init of fc out region ----------------
// grid 512 x 256 = 131072 threads: each zeroes 4 float4 of out[0 : 512*4096);
// threads with gid < 65536 also cast/swizzle one weight element. Idempotent per replay.
__global__ __launch_bounds__(256) void k0_weights(
    const float* __restrict__ Wq, const float* __restrict__ Wk,
    const float* __restrict__ Wfc,
    __bf16* __restrict__ wq, __bf16* __restrict__ wk, __bf16* __restrict__ wfc,
    float* __restrict__ out) {
  int i = blockIdx.x * 256 + threadIdx.x;
  float4 z = make_float4(0.f, 0.f, 0.f, 0.f);
#pragma unroll
  for (int j = 0; j < 4; ++j) reinterpret_cast<float4*>(out)[i + j * 131072] = z;
  if (i < 16384) {
    int e = i >> 6, k = i & 63;
    int dst = ((e >> 4) * 2 + (k >> 5)) * 512 + (e & 15) * 32 + (k & 31);
    wq[dst] = (__bf16)(Wq[i] * 0.015625f);
  } else if (i < 32768) {
    int j = i - 16384;
    int e = j >> 6, k = j & 63;
    int dst = ((e >> 4) * 2 + (k >> 5)) * 512 + (e & 15) * 32 + (k & 31);
    wk[dst] = (__bf16)Wk[j];
  } else if (i < 65536) {
    int j = i - 32768;
    int o = j >> 9, f = j & 511;
    int dst = ((o >> 4) * 16 + (f >> 5)) * 512 + (o & 15) * 32 + (f & 31);
    wfc[dst] = (__bf16)Wfc[j];
  }
}

// ---------------- K1: fused kernel, 4 heads per block, 2 blocks per b ----------------
// grid (512, 2): block (b, half) does heads [4*half, 4*half+4). 256 threads.
// LDS 39,952 B -> EXACTLY 4 blocks/CU resident (16 waves/CU) -> grid fits in ONE
// scheduling round (1024 blocks / 256 CUs = 4/CU). q is register-resident via
// operand-swapped qGEMM + in-wave shfl transpose (s_q buffer eliminated).
// fc partials combined via fp32 atomicAdd into the k0-zeroed out region.
__global__ __launch_bounds__(256, 4) void k_fused(
    const float* __restrict__ feat, const int* __restrict__ sidx,
    const float* __restrict__ gamma, const float* __restrict__ beta,
    const __bf16* __restrict__ wq, const __bf16* __restrict__ wk,
    const float* __restrict__ Wv1, const float* __restrict__ Wv2,
    const __bf16* __restrict__ wfc, float* __restrict__ out) {
  __shared__ __align__(16) __bf16 smem[19968];  // 39,936 B
  __shared__ float red[4];
  __bf16* s_feat = smem;           // 4096   raw features bf16 (gather source, all heads)
  __bf16* s_qin  = smem + 4096;    // 4096   LN output, tile-swizzled (all heads)
  __bf16* s_kf   = smem + 8192;    // 64x72  gathered kf; aliased as scores + fc staging
  __bf16* s_K    = smem + 12800;   // 64x40
  __bf16* s_vT   = smem + 15360;   // 64x72  v^T [s][n]
  __bf16* s_sc   = s_kf;           // alias: s_kf dead once scores start

  const int b = blockIdx.x, half = blockIdx.y, h0 = 4 * half;
  const int t = threadIdx.x, w = t >> 6, lane = t & 63;
  const int quad = lane >> 4, l16 = lane & 15;

  // ---- LN phase (+ prefetch first head's gather indices) ----
  const float4* frow4 = reinterpret_cast<const float4*>(feat + (size_t)b * kM);
  const float4* g4  = reinterpret_cast<const float4*>(gamma);
  const float4* be4 = reinterpret_cast<const float4*>(beta);
  float4 xs[4];
  float s = 0.f;
#pragma unroll
  for (int j = 0; j < 4; ++j) {
    xs[j] = frow4[t + j * 256];
    s += xs[j].x + xs[j].y + xs[j].z + xs[j].w;
  }
  int idxr[16], idxn[16];
#pragma unroll
  for (int j = 0; j < 16; ++j) idxr[j] = sidx[(size_t)h0 * kM + t + j * 256];
#pragma unroll
  for (int o = 32; o > 0; o >>= 1) s += __shfl_xor(s, o);
  if (lane == 0) red[w] = s;
  __syncthreads();
  const float mu = (red[0] + red[1] + red[2] + red[3]) * (1.f / kM);
  float var_p = 0.f;
#pragma unroll
  for (int j = 0; j < 4; ++j) {
    float d0 = xs[j].x - mu, d1 = xs[j].y - mu, d2 = xs[j].z - mu, d3 = xs[j].w - mu;
    var_p += d0 * d0 + d1 * d1 + d2 * d2 + d3 * d3;
  }
#pragma unroll
  for (int o = 32; o > 0; o >>= 1) var_p += __shfl_xor(var_p, o);
  __syncthreads();
  if (lane == 0) red[w] = var_p;
  __syncthreads();
  const float var  = (red[0] + red[1] + red[2] + red[3]) * (1.f / kM);
  const float rstd = rsqrtf(var + 1e-5f);
#pragma unroll
  for (int j = 0; j < 4; ++j) {
    const int i4 = t + j * 256;
    float4 g = g4[i4], bt = be4[i4];
    v4bf fb, qb;
    fb[0] = (__bf16)xs[j].x; fb[1] = (__bf16)xs[j].y;
    fb[2] = (__bf16)xs[j].z; fb[3] = (__bf16)xs[j].w;
    qb[0] = (__bf16)((xs[j].x - mu) * rstd * g.x + bt.x);
    qb[1] = (__bf16)((xs[j].y - mu) * rstd * g.y + bt.y);
    qb[2] = (__bf16)((xs[j].z - mu) * rstd * g.z + bt.z);
    qb[3] = (__bf16)((xs[j].w - mu) * rstd * g.w + bt.w);
    *(v4bf*)(s_feat + 4 * i4) = fb;
    // element m = 4*i4 + c -> n = i4>>4, k = 4*(t&15) + c
    const int n = i4 >> 4, k = 4 * (t & 15);
    const int dst = ((n >> 4) * 2 + (k >> 5)) * 512 + (n & 15) * 32 + (k & 31);
    *(v4bf*)(s_qin + dst) = qb;
  }
  __syncthreads();  // bar0: s_feat, s_qin ready

  v4f acc[4] = {{0.f, 0.f, 0.f, 0.f}, {0.f, 0.f, 0.f, 0.f},
                {0.f, 0.f, 0.f, 0.f}, {0.f, 0.f, 0.f, 0.f}};  // fc partial (this half)

  for (int it = 0; it < 4; ++it) {
    const int h = h0 + it;

    // ---- q-GEMM, operand-swapped: qT = mfma(A=wq, B=qin) -> C[e][n], cols n=l16.
    // Then in-wave shfl transpose builds the scores A-fragment (row n=l16, k-octet=quad).
    // No LDS, no barrier dependence.
    v8bf aq;
    {
      v4f dq0 = {0.f, 0.f, 0.f, 0.f}, dq1 = {0.f, 0.f, 0.f, 0.f};
#pragma unroll
      for (int kt = 0; kt < 2; ++kt) {
        v8bf a  = *(const v8bf*)(s_qin + (2 * w + kt) * 512 + l16 * 32 + 8 * quad);
        v8bf b0 = *(const v8bf*)(wq + (size_t)(4 * h + kt) * 512 + l16 * 32 + 8 * quad);
        v8bf b1 = *(const v8bf*)(wq + (size_t)(4 * h + 2 + kt) * 512 + l16 * 32 + 8 * quad);
        dq0 = __builtin_amdgcn_mfma_f32_16x16x32_bf16(b0, a, dq0, 0, 0, 0);
        dq1 = __builtin_amdgcn_mfma_f32_16x16x32_bf16(b1, a, dq1, 0, 0, 0);
      }
      // lane (l16, q') holds q[16w+l16][d], d in {4q'..4q'+3} (p0) u {16+4q'..16+4q'+3} (p1)
      v4bf p0, p1;
#pragma unroll
      for (int r = 0; r < 4; ++r) { p0[r] = (__bf16)dq0[r]; p1[r] = (__bf16)dq1[r]; }
      const u64 P0 = __builtin_bit_cast(u64, p0), P1 = __builtin_bit_cast(u64, p1);
      const int qs = 16 * (2 * (quad & 1));
      u64 s0p0 = __shfl(P0, l16 + qs),      s0p1 = __shfl(P1, l16 + qs);
      u64 s1p0 = __shfl(P0, l16 + qs + 16), s1p1 = __shfl(P1, l16 + qs + 16);
      v4bf lo = __builtin_bit_cast(v4bf, (quad >> 1) ? s0p1 : s0p0);
      v4bf hi = __builtin_bit_cast(v4bf, (quad >> 1) ? s1p1 : s1p0);
#pragma unroll
      for (int r = 0; r < 4; ++r) { aq[r] = lo[r]; aq[4 + r] = hi[r]; }
    }

    // ---- prefetch next head's gather indices (overlaps everything below)
    if (it < 3) {
      const int* idxp = sidx + (size_t)(h + 1) * kM;
#pragma unroll
      for (int j = 0; j < 16; ++j) idxn[j] = idxp[t + j * 256];
    }

    // ---- gather kf from LDS (random b16 reads on the crossbar)
#pragma unroll
    for (int j = 0; j < 16; ++j) {
      int i = t + j * 256;
      s_kf[(i >> 6) * 72 + (i & 63)] = s_feat[idxr[j]];
    }
    // re-zero conv pad cols 64..71 every iteration (fc staging clobbers them)
    if (t < 64) { v8bf z = {}; *(v8bf*)(s_kf + t * 72 + 64) = z; }
    __syncthreads();  // bar1: s_kf ready

    // ---- K-GEMM
    {
      v4f dk0 = {0.f, 0.f, 0.f, 0.f}, dk1 = {0.f, 0.f, 0.f, 0.f};
#pragma unroll
      for (int kt = 0; kt < 2; ++kt) {
        v8bf a  = *(const v8bf*)(s_kf + (16 * w + l16) * 72 + 32 * kt + 8 * quad);
        v8bf b0 = *(const v8bf*)(wk + (size_t)(4 * h + kt) * 512 + l16 * 32 + 8 * quad);
        v8bf b1 = *(const v8bf*)(wk + (size_t)(4 * h + 2 + kt) * 512 + l16 * 32 + 8 * quad);
        dk0 = __builtin_amdgcn_mfma_f32_16x16x32_bf16(a, b0, dk0, 0, 0, 0);
        dk1 = __builtin_amdgcn_mfma_f32_16x16x32_bf16(a, b1, dk1, 0, 0, 0);
      }
#pragma unroll
      for (int r = 0; r < 4; ++r) {
        s_K[(16 * w + 4 * quad + r) * 40 + l16]      = (__bf16)dk0[r];
        s_K[(16 * w + 4 * quad + r) * 40 + 16 + l16] = (__bf16)dk1[r];
      }
    }

    // ---- windowed conv + relu + residual, written transposed (v^T[s][n])
    {
      const int n = lane, p0c = w * 16;
      float w1[4][3], w2[4];
#pragma unroll
      for (int d = 0; d < 4; ++d) {
#pragma unroll
        for (int c = 0; c < 3; ++c) w1[d][c] = Wv1[(h * 4 + d) * 3 + c];
        w2[d] = Wv2[h * 4 + d];
      }
      v8bf xa = *(const v8bf*)(s_kf + n * 72 + p0c);
      v8bf xb = *(const v8bf*)(s_kf + n * 72 + p0c + 8);
      v2bf xc = *(const v2bf*)(s_kf + n * 72 + p0c + 16);  // pad cols re-zeroed above
      float x[18];
#pragma unroll
      for (int c = 0; c < 8; ++c) { x[c] = (float)xa[c]; x[c + 8] = (float)xb[c]; }
      x[16] = (float)xc[0]; x[17] = (float)xc[1];
#pragma unroll
      for (int pp = 0; pp < 16; ++pp) {
        float a0 = x[pp];
#pragma unroll
        for (int d = 0; d < 4; ++d) {
          float v1 = fmaf(x[pp + 2], w1[d][2], fmaf(x[pp + 1], w1[d][1], x[pp] * w1[d][0]));
          a0 = fmaf(fmaxf(v1, 0.f), w2[d], a0);
        }
        s_vT[(p0c + pp) * 72 + n] = (__bf16)a0;
      }
    }
    __syncthreads();  // bar2: s_K, s_vT ready; all s_kf readers done (s_sc alias safe)

    // ---- scores[qi][n] = q[qi][d] * K[n][d]  (q from registers: aq)
    {
      v4f ds[4] = {{0.f, 0.f, 0.f, 0.f}, {0.f, 0.f, 0.f, 0.f},
                   {0.f, 0.f, 0.f, 0.f}, {0.f, 0.f, 0.f, 0.f}};
#pragma unroll
      for (int nt = 0; nt < 4; ++nt) {
        v8bf bb = *(const v8bf*)(s_K + (16 * nt + l16) * 40 + 8 * quad);
        ds[nt] = __builtin_amdgcn_mfma_f32_16x16x32_bf16(aq, bb, ds[nt], 0, 0, 0);
      }
#pragma unroll
      for (int nt = 0; nt < 4; ++nt)
#pragma unroll
        for (int r = 0; r < 4; ++r)
          s_sc[(16 * w + 4 * quad + r) * 72 + 16 * nt + l16] = (__bf16)ds[nt][r];
    }
    // no barrier: wave w owns rows 16w..16w+15 of s_sc end-to-end

    // ---- softmax + attn output
    float* attn_out = out + (size_t)kB * kM + ((size_t)(b * kH + h)) * 4096;
#pragma unroll
    for (int rr = 0; rr < 4; ++rr) {
      const int row = 16 * w + 4 * rr + quad;
      v4bf pv = *(const v4bf*)(s_sc + row * 72 + 4 * l16);
      float e0 = (float)pv[0], e1 = (float)pv[1], e2 = (float)pv[2], e3 = (float)pv[3];
      float mx = fmaxf(fmaxf(e0, e1), fmaxf(e2, e3));
#pragma unroll
      for (int mk = 8; mk > 0; mk >>= 1) mx = fmaxf(mx, __shfl_xor(mx, mk));
      e0 = __expf(e0 - mx); e1 = __expf(e1 - mx);
      e2 = __expf(e2 - mx); e3 = __expf(e3 - mx);
      float ssum = e0 + e1 + e2 + e3;
#pragma unroll
      for (int mk = 8; mk > 0; mk >>= 1) ssum += __shfl_xor(ssum, mk);
      const float inv = 1.0f / ssum;
      e0 *= inv; e1 *= inv; e2 *= inv; e3 *= inv;
      *(float4*)(attn_out + row * 64 + 4 * l16) = make_float4(e0, e1, e2, e3);
      v4bf st;
      st[0] = (__bf16)e0; st[1] = (__bf16)e1; st[2] = (__bf16)e2; st[3] = (__bf16)e3;
      *(v4bf*)(s_sc + row * 72 + 4 * l16) = st;
    }

    // ---- PV: o[qi][s] = attn[qi][n] * vT[s][n]
    v4f dO[4] = {{0.f, 0.f, 0.f, 0.f}, {0.f, 0.f, 0.f, 0.f},
                 {0.f, 0.f, 0.f, 0.f}, {0.f, 0.f, 0.f, 0.f}};
#pragma unroll
    for (int kt = 0; kt < 2; ++kt) {
      v8bf a = *(const v8bf*)(s_sc + (16 * w + l16) * 72 + 32 * kt + 8 * quad);
#pragma unroll
      for (int st = 0; st < 4; ++st) {
        v8bf bb = *(const v8bf*)(s_vT + (16 * st + l16) * 72 + 32 * kt + 8 * quad);
        dO[st] = __builtin_amdgcn_mfma_f32_16x16x32_bf16(a, bb, dO[st], 0, 0, 0);
      }
    }

    // ---- fc partial: acc[n][o] += o_h[n][k] * Wfc[o][h*64+k]
    // o round-trips through the wave's own dead s_sc slice (wave-private rows).
    {
      __bf16* ob = s_kf + w * 1152;  // rows 16w..16w+15 of s_sc (72-stride region)
#pragma unroll
      for (int st = 0; st < 4; ++st)
#pragma unroll
        for (int r = 0; r < 4; ++r)
          ob[(st >> 1) * 512 + (4 * quad + r) * 32 + (st & 1) * 16 + l16] = (__bf16)dO[st][r];
#pragma unroll
      for (int kt = 0; kt < 2; ++kt) {
        v8bf a = *(const v8bf*)(ob + kt * 512 + l16 * 32 + 8 * quad);
#pragma unroll
        for (int nt = 0; nt < 4; ++nt) {
          v8bf bb = *(const v8bf*)(wfc + (size_t)(nt * 16 + h * 2 + kt) * 512 + l16 * 32 + 8 * quad);
          acc[nt] = __builtin_amdgcn_mfma_f32_16x16x32_bf16(a, bb, acc[nt], 0, 0, 0);
        }
      }
    }
    __syncthreads();  // bar3: all cross-wave reads done before next head's writes

    if (it < 3) {
#pragma unroll
      for (int j = 0; j < 16; ++j) idxr[j] = idxn[j];
    }
  }

  // ---- combine fc partials across the two half-blocks via atomicAdd (out pre-zeroed by k0)
  float* orow = out + (size_t)b * kM;
#pragma unroll
  for (int nt = 0; nt < 4; ++nt)
#pragma unroll
    for (int r = 0; r < 4; ++r)
      atomicAdd(&orow[(16 * w + 4 * quad + r) * 64 + 16 * nt + l16], acc[nt][r]);
}

}  // namespace

extern "C" void kernel_launch(void* const* d_in, const int* in_sizes, int n_in,
                              void* d_out, int out_size, void* d_ws, size_t ws_size,
                              hipStream_t stream) {
  (void)in_sizes; (void)n_in; (void)out_size; (void)ws_size;
  const float* features = (const float*)d_in[0];
  const int*   sidx     = (const int*)d_in[1];
  const float* gamma    = (const float*)d_in[2];
  const float* beta     = (const float*)d_in[3];
  const float* Wq       = (const float*)d_in[4];
  const float* Wk       = (const float*)d_in[5];
  const float* Wv1      = (const float*)d_in[6];
  const float* Wv2      = (const float*)d_in[7];
  const float* Wfc      = (const float*)d_in[8];
  float* out = (float*)d_out;

  char* ws = (char*)d_ws;
  __bf16* ws_wq  = (__bf16*)(ws);
  __bf16* ws_wk  = (__bf16*)(ws + 32768);
  __bf16* ws_wfc = (__bf16*)(ws + 65536);

  hipLaunchKernelGGL(k0_weights, dim3(512), dim3(256), 0, stream,
                     Wq, Wk, Wfc, ws_wq, ws_wk, ws_wfc, out);
  hipLaunchKernelGGL(k_fused, dim3(kB, 2), dim3(256), 0, stream,
                     features, sidx, gamma, beta, ws_wq, ws_wk, Wv1, Wv2, ws_wfc, out);
}

// Round 5
// 136.191 us; speedup vs baseline: 1.1615x; 1.0740x over previous
//
#include <hip/hip_runtime.h>

typedef __bf16 v8bf __attribute__((ext_vector_type(8)));
typedef __bf16 v4bf __attribute__((ext_vector_type(4)));
typedef __bf16 v2bf __attribute__((ext_vector_type(2)));
typedef float  v4f  __attribute__((ext_vector_type(4)));
typedef float  v2f  __attribute__((ext_vector_type(2)));
typedef unsigned long long u64;

namespace {

constexpr int kB = 512, kM = 4096, kH = 8;

// ws layout (bytes): wq 32KB @ 0, wk 32KB @ 32768, wfc 64KB @ 65536
// Tile swizzle: element (r, c) of a row-major [R x C] matrix lives at
//   tile = (r>>4)*(C/32) + (c>>5);  addr = tile*512 + (r&15)*32 + (c&31)

// ---------------- K0: weight casts + swizzle + zero-init of fc out region ----------------
__global__ __launch_bounds__(256) void k0_weights(
    const float* __restrict__ Wq, const float* __restrict__ Wk,
    const float* __restrict__ Wfc,
    __bf16* __restrict__ wq, __bf16* __restrict__ wk, __bf16* __restrict__ wfc,
    float* __restrict__ out) {
  int i = blockIdx.x * 256 + threadIdx.x;
  float4 z = make_float4(0.f, 0.f, 0.f, 0.f);
#pragma unroll
  for (int j = 0; j < 4; ++j) reinterpret_cast<float4*>(out)[i + j * 131072] = z;
  if (i < 16384) {
    int e = i >> 6, k = i & 63;
    int dst = ((e >> 4) * 2 + (k >> 5)) * 512 + (e & 15) * 32 + (k & 31);
    wq[dst] = (__bf16)(Wq[i] * 0.015625f);
  } else if (i < 32768) {
    int j = i - 16384;
    int e = j >> 6, k = j & 63;
    int dst = ((e >> 4) * 2 + (k >> 5)) * 512 + (e & 15) * 32 + (k & 31);
    wk[dst] = (__bf16)Wk[j];
  } else if (i < 65536) {
    int j = i - 32768;
    int o = j >> 9, f = j & 511;
    int dst = ((o >> 4) * 16 + (f >> 5)) * 512 + (o & 15) * 32 + (f & 31);
    wfc[dst] = (__bf16)Wfc[j];
  }
}

// ---------------- K1: fused kernel, 4 heads per block, 2 blocks per b ----------------
// grid (512, 2), 256 threads, LDS 40448 B -> 4 blocks/CU, one scheduling round.
// Wave-private gather straight into K-GEMM fragments; swapped K-GEMM with packed
// b64 K stores; float2-packed conv. 3 barriers/head.
__global__ __launch_bounds__(256, 4) void k_fused(
    const float* __restrict__ feat, const int* __restrict__ sidx,
    const float* __restrict__ gamma, const float* __restrict__ beta,
    const __bf16* __restrict__ wq, const __bf16* __restrict__ wk,
    const float* __restrict__ Wv1, const float* __restrict__ Wv2,
    const __bf16* __restrict__ wfc, float* __restrict__ out) {
  __shared__ __align__(16) __bf16 smem[19968];  // 39,936 B
  __shared__ float red[4];
  __bf16* s_feat = smem;           // 4096   raw features bf16 (gather source, all heads)
  __bf16* s_qin  = smem + 4096;    // 4096   LN output, tile-swizzled (all heads)
  __bf16* s_kf   = smem + 8192;    // 64x72  gathered kf; aliased as scores + fc staging
  __bf16* s_K    = smem + 12800;   // 64x40  K[n][d]
  __bf16* s_vT   = smem + 15360;   // 64x72  v^T [s][n]
  __bf16* s_sc   = s_kf;           // alias: s_kf dead once scores start

  const int b = blockIdx.x, half = blockIdx.y, h0 = 4 * half;
  const int t = threadIdx.x, w = t >> 6, lane = t & 63;
  const int quad = lane >> 4, l16 = lane & 15;
  const int myrow = 16 * w + l16;  // kf/K row owned by this lane

  // ---- LN phase (+ prefetch first head's gather indices, vectorized) ----
  const float4* frow4 = reinterpret_cast<const float4*>(feat + (size_t)b * kM);
  const float4* g4  = reinterpret_cast<const float4*>(gamma);
  const float4* be4 = reinterpret_cast<const float4*>(beta);
  float4 xs[4];
  float s = 0.f;
#pragma unroll
  for (int j = 0; j < 4; ++j) {
    xs[j] = frow4[t + j * 256];
    s += xs[j].x + xs[j].y + xs[j].z + xs[j].w;
  }
  // indices for this lane's K-GEMM fragments: rows myrow, cols 32kt+8quad+4p
  int4 idxc[4], idxn[4];
  {
    const int* ibase = sidx + (size_t)h0 * kM + myrow * 64 + 8 * quad;
#pragma unroll
    for (int p = 0; p < 4; ++p)
      idxc[p] = *(const int4*)(ibase + 32 * (p >> 1) + 4 * (p & 1));
  }
#pragma unroll
  for (int o = 32; o > 0; o >>= 1) s += __shfl_xor(s, o);
  if (lane == 0) red[w] = s;
  __syncthreads();
  const float mu = (red[0] + red[1] + red[2] + red[3]) * (1.f / kM);
  float var_p = 0.f;
#pragma unroll
  for (int j = 0; j < 4; ++j) {
    float d0 = xs[j].x - mu, d1 = xs[j].y - mu, d2 = xs[j].z - mu, d3 = xs[j].w - mu;
    var_p += d0 * d0 + d1 * d1 + d2 * d2 + d3 * d3;
  }
#pragma unroll
  for (int o = 32; o > 0; o >>= 1) var_p += __shfl_xor(var_p, o);
  __syncthreads();
  if (lane == 0) red[w] = var_p;
  __syncthreads();
  const float var  = (red[0] + red[1] + red[2] + red[3]) * (1.f / kM);
  const float rstd = rsqrtf(var + 1e-5f);
#pragma unroll
  for (int j = 0; j < 4; ++j) {
    const int i4 = t + j * 256;
    float4 g = g4[i4], bt = be4[i4];
    v4bf fb, qb;
    fb[0] = (__bf16)xs[j].x; fb[1] = (__bf16)xs[j].y;
    fb[2] = (__bf16)xs[j].z; fb[3] = (__bf16)xs[j].w;
    qb[0] = (__bf16)((xs[j].x - mu) * rstd * g.x + bt.x);
    qb[1] = (__bf16)((xs[j].y - mu) * rstd * g.y + bt.y);
    qb[2] = (__bf16)((xs[j].z - mu) * rstd * g.z + bt.z);
    qb[3] = (__bf16)((xs[j].w - mu) * rstd * g.w + bt.w);
    *(v4bf*)(s_feat + 4 * i4) = fb;
    const int n = i4 >> 4, k = 4 * (t & 15);
    const int dst = ((n >> 4) * 2 + (k >> 5)) * 512 + (n & 15) * 32 + (k & 31);
    *(v4bf*)(s_qin + dst) = qb;
  }
  __syncthreads();  // bar0: s_feat, s_qin ready

  v4f acc[4] = {{0.f, 0.f, 0.f, 0.f}, {0.f, 0.f, 0.f, 0.f},
                {0.f, 0.f, 0.f, 0.f}, {0.f, 0.f, 0.f, 0.f}};  // fc partial (this half)

  for (int it = 0; it < 4; ++it) {
    const int h = h0 + it;

    // ---- q-GEMM, operand-swapped (round-4 proven): q register-resident as aq
    v8bf aq;
    {
      v4f dq0 = {0.f, 0.f, 0.f, 0.f}, dq1 = {0.f, 0.f, 0.f, 0.f};
#pragma unroll
      for (int kt = 0; kt < 2; ++kt) {
        v8bf a  = *(const v8bf*)(s_qin + (2 * w + kt) * 512 + l16 * 32 + 8 * quad);
        v8bf b0 = *(const v8bf*)(wq + (size_t)(4 * h + kt) * 512 + l16 * 32 + 8 * quad);
        v8bf b1 = *(const v8bf*)(wq + (size_t)(4 * h + 2 + kt) * 512 + l16 * 32 + 8 * quad);
        dq0 = __builtin_amdgcn_mfma_f32_16x16x32_bf16(b0, a, dq0, 0, 0, 0);
        dq1 = __builtin_amdgcn_mfma_f32_16x16x32_bf16(b1, a, dq1, 0, 0, 0);
      }
      v4bf p0, p1;
#pragma unroll
      for (int r = 0; r < 4; ++r) { p0[r] = (__bf16)dq0[r]; p1[r] = (__bf16)dq1[r]; }
      const u64 P0 = __builtin_bit_cast(u64, p0), P1 = __builtin_bit_cast(u64, p1);
      const int qs = 16 * (2 * (quad & 1));
      u64 s0p0 = __shfl(P0, l16 + qs),      s0p1 = __shfl(P1, l16 + qs);
      u64 s1p0 = __shfl(P0, l16 + qs + 16), s1p1 = __shfl(P1, l16 + qs + 16);
      v4bf lo = __builtin_bit_cast(v4bf, (quad >> 1) ? s0p1 : s0p0);
      v4bf hi = __builtin_bit_cast(v4bf, (quad >> 1) ? s1p1 : s1p0);
#pragma unroll
      for (int r = 0; r < 4; ++r) { aq[r] = lo[r]; aq[4 + r] = hi[r]; }
    }

    // ---- prefetch next head's gather indices (4 x int4)
    if (it < 3) {
      const int* ibase = sidx + (size_t)(h + 1) * kM + myrow * 64 + 8 * quad;
#pragma unroll
      for (int p = 0; p < 4; ++p)
        idxn[p] = *(const int4*)(ibase + 32 * (p >> 1) + 4 * (p & 1));
    }

    // ---- gather straight into K-GEMM kf fragments (wave-private rows myrow)
    v8bf a0, a1;
    a0[0] = s_feat[idxc[0].x]; a0[1] = s_feat[idxc[0].y];
    a0[2] = s_feat[idxc[0].z]; a0[3] = s_feat[idxc[0].w];
    a0[4] = s_feat[idxc[1].x]; a0[5] = s_feat[idxc[1].y];
    a0[6] = s_feat[idxc[1].z]; a0[7] = s_feat[idxc[1].w];
    a1[0] = s_feat[idxc[2].x]; a1[1] = s_feat[idxc[2].y];
    a1[2] = s_feat[idxc[2].z]; a1[3] = s_feat[idxc[2].w];
    a1[4] = s_feat[idxc[3].x]; a1[5] = s_feat[idxc[3].y];
    a1[6] = s_feat[idxc[3].z]; a1[7] = s_feat[idxc[3].w];
    // dump to s_kf for conv (vector stores; cols 8quad / 32+8quad of own row)
    *(v8bf*)(s_kf + myrow * 72 + 8 * quad)      = a0;
    *(v8bf*)(s_kf + myrow * 72 + 32 + 8 * quad) = a1;
    // re-zero conv pad cols 64..71 (fc staging clobbers them each iteration)
    if (t < 64) { v8bf z = {}; *(v8bf*)(s_kf + t * 72 + 64) = z; }

    // ---- K-GEMM, operand-swapped: C[d][n], lane holds 4 consecutive d of own row
    {
      v4f dk0 = {0.f, 0.f, 0.f, 0.f}, dk1 = {0.f, 0.f, 0.f, 0.f};
      v8bf b00 = *(const v8bf*)(wk + (size_t)(4 * h + 0) * 512 + l16 * 32 + 8 * quad);
      v8bf b10 = *(const v8bf*)(wk + (size_t)(4 * h + 2) * 512 + l16 * 32 + 8 * quad);
      dk0 = __builtin_amdgcn_mfma_f32_16x16x32_bf16(b00, a0, dk0, 0, 0, 0);
      dk1 = __builtin_amdgcn_mfma_f32_16x16x32_bf16(b10, a0, dk1, 0, 0, 0);
      v8bf b01 = *(const v8bf*)(wk + (size_t)(4 * h + 1) * 512 + l16 * 32 + 8 * quad);
      v8bf b11 = *(const v8bf*)(wk + (size_t)(4 * h + 3) * 512 + l16 * 32 + 8 * quad);
      dk0 = __builtin_amdgcn_mfma_f32_16x16x32_bf16(b01, a1, dk0, 0, 0, 0);
      dk1 = __builtin_amdgcn_mfma_f32_16x16x32_bf16(b11, a1, dk1, 0, 0, 0);
      v4bf p0, p1;
#pragma unroll
      for (int r = 0; r < 4; ++r) { p0[r] = (__bf16)dk0[r]; p1[r] = (__bf16)dk1[r]; }
      *(v4bf*)(s_K + myrow * 40 + 4 * quad)      = p0;  // K[myrow][4quad+r]
      *(v4bf*)(s_K + myrow * 40 + 16 + 4 * quad) = p1;  // K[myrow][16+4quad+r]
    }
    __syncthreads();  // bar A: s_kf (all rows) + s_K ready

    // ---- windowed conv + relu + residual, float2-packed (pp and pp+8), vT[s][n]
    {
      const int n = lane, p0c = w * 16;
      float w1[4][3], w2[4];
#pragma unroll
      for (int d = 0; d < 4; ++d) {
#pragma unroll
        for (int c = 0; c < 3; ++c) w1[d][c] = Wv1[(h * 4 + d) * 3 + c];
        w2[d] = Wv2[h * 4 + d];
      }
      v8bf xa = *(const v8bf*)(s_kf + n * 72 + p0c);
      v8bf xb = *(const v8bf*)(s_kf + n * 72 + p0c + 8);
      v2bf xc = *(const v2bf*)(s_kf + n * 72 + p0c + 16);  // pad cols zeroed
      v2f x2[10];
#pragma unroll
      for (int j = 0; j < 8; ++j) { x2[j][0] = (float)xa[j]; x2[j][1] = (float)xb[j]; }
      x2[8][0] = (float)xb[0]; x2[8][1] = (float)xc[0];
      x2[9][0] = (float)xb[1]; x2[9][1] = (float)xc[1];
      const v2f z2 = {0.f, 0.f};
#pragma unroll
      for (int pp = 0; pp < 8; ++pp) {
        v2f a2 = x2[pp];
#pragma unroll
        for (int d = 0; d < 4; ++d) {
          v2f v1 = x2[pp] * w1[d][0] + x2[pp + 1] * w1[d][1] + x2[pp + 2] * w1[d][2];
          v1 = __builtin_elementwise_max(v1, z2);
          a2 = a2 + v1 * w2[d];
        }
        s_vT[(p0c + pp) * 72 + n]     = (__bf16)a2[0];
        s_vT[(p0c + pp + 8) * 72 + n] = (__bf16)a2[1];
      }
    }
    __syncthreads();  // bar B: s_vT ready; all s_kf readers done (s_sc alias safe)

    // ---- scores[qi][n] = q[qi][d] * K[n][d]  (q from registers: aq)
    {
      v4f ds[4] = {{0.f, 0.f, 0.f, 0.f}, {0.f, 0.f, 0.f, 0.f},
                   {0.f, 0.f, 0.f, 0.f}, {0.f, 0.f, 0.f, 0.f}};
#pragma unroll
      for (int nt = 0; nt < 4; ++nt) {
        v8bf bb = *(const v8bf*)(s_K + (16 * nt + l16) * 40 + 8 * quad);
        ds[nt] = __builtin_amdgcn_mfma_f32_16x16x32_bf16(aq, bb, ds[nt], 0, 0, 0);
      }
#pragma unroll
      for (int nt = 0; nt < 4; ++nt)
#pragma unroll
        for (int r = 0; r < 4; ++r)
          s_sc[(16 * w + 4 * quad + r) * 72 + 16 * nt + l16] = (__bf16)ds[nt][r];
    }
    // no barrier: wave w owns rows 16w..16w+15 of s_sc end-to-end

    // ---- softmax + attn output
    float* attn_out = out + (size_t)kB * kM + ((size_t)(b * kH + h)) * 4096;
#pragma unroll
    for (int rr = 0; rr < 4; ++rr) {
      const int row = 16 * w + 4 * rr + quad;
      v4bf pv = *(const v4bf*)(s_sc + row * 72 + 4 * l16);
      float e0 = (float)pv[0], e1 = (float)pv[1], e2 = (float)pv[2], e3 = (float)pv[3];
      float mx = fmaxf(fmaxf(e0, e1), fmaxf(e2, e3));
#pragma unroll
      for (int mk = 8; mk > 0; mk >>= 1) mx = fmaxf(mx, __shfl_xor(mx, mk));
      e0 = __expf(e0 - mx); e1 = __expf(e1 - mx);
      e2 = __expf(e2 - mx); e3 = __expf(e3 - mx);
      float ssum = e0 + e1 + e2 + e3;
#pragma unroll
      for (int mk = 8; mk > 0; mk >>= 1) ssum += __shfl_xor(ssum, mk);
      const float inv = 1.0f / ssum;
      e0 *= inv; e1 *= inv; e2 *= inv; e3 *= inv;
      *(float4*)(attn_out + row * 64 + 4 * l16) = make_float4(e0, e1, e2, e3);
      v4bf st;
      st[0] = (__bf16)e0; st[1] = (__bf16)e1; st[2] = (__bf16)e2; st[3] = (__bf16)e3;
      *(v4bf*)(s_sc + row * 72 + 4 * l16) = st;
    }

    // ---- PV: o[qi][s] = attn[qi][n] * vT[s][n]
    v4f dO[4] = {{0.f, 0.f, 0.f, 0.f}, {0.f, 0.f, 0.f, 0.f},
                 {0.f, 0.f, 0.f, 0.f}, {0.f, 0.f, 0.f, 0.f}};
#pragma unroll
    for (int kt = 0; kt < 2; ++kt) {
      v8bf a = *(const v8bf*)(s_sc + (16 * w + l16) * 72 + 32 * kt + 8 * quad);
#pragma unroll
      for (int st = 0; st < 4; ++st) {
        v8bf bb = *(const v8bf*)(s_vT + (16 * st + l16) * 72 + 32 * kt + 8 * quad);
        dO[st] = __builtin_amdgcn_mfma_f32_16x16x32_bf16(a, bb, dO[st], 0, 0, 0);
      }
    }

    // ---- fc partial: acc[n][o] += o_h[n][k] * Wfc[o][h*64+k]
    {
      __bf16* ob = s_kf + w * 1152;  // wave-private rows 16w..16w+15 of s_sc region
#pragma unroll
      for (int st = 0; st < 4; ++st)
#pragma unroll
        for (int r = 0; r < 4; ++r)
          ob[(st >> 1) * 512 + (4 * quad + r) * 32 + (st & 1) * 16 + l16] = (__bf16)dO[st][r];
#pragma unroll
      for (int kt = 0; kt < 2; ++kt) {
        v8bf a = *(const v8bf*)(ob + kt * 512 + l16 * 32 + 8 * quad);
#pragma unroll
        for (int nt = 0; nt < 4; ++nt) {
          v8bf bb = *(const v8bf*)(wfc + (size_t)(nt * 16 + h * 2 + kt) * 512 + l16 * 32 + 8 * quad);
          acc[nt] = __builtin_amdgcn_mfma_f32_16x16x32_bf16(a, bb, acc[nt], 0, 0, 0);
        }
      }
    }
    __syncthreads();  // bar C: scores' s_K reads + PV's s_vT reads done before next head

    if (it < 3) {
#pragma unroll
      for (int p = 0; p < 4; ++p) idxc[p] = idxn[p];
    }
  }

  // ---- combine fc partials across the two half-blocks via atomicAdd (out pre-zeroed by k0)
  float* orow = out + (size_t)b * kM;
#pragma unroll
  for (int nt = 0; nt < 4; ++nt)
#pragma unroll
    for (int r = 0; r < 4; ++r)
      atomicAdd(&orow[(16 * w + 4 * quad + r) * 64 + 16 * nt + l16], acc[nt][r]);
}

}  // namespace

extern "C" void kernel_launch(void* const* d_in, const int* in_sizes, int n_in,
                              void* d_out, int out_size, void* d_ws, size_t ws_size,
                              hipStream_t stream) {
  (void)in_sizes; (void)n_in; (void)out_size; (void)ws_size;
  const float* features = (const float*)d_in[0];
  const int*   sidx     = (const int*)d_in[1];
  const float* gamma    = (const float*)d_in[2];
  const float* beta     = (const float*)d_in[3];
  const float* Wq       = (const float*)d_in[4];
  const float* Wk       = (const float*)d_in[5];
  const float* Wv1      = (const float*)d_in[6];
  const float* Wv2      = (const float*)d_in[7];
  const float* Wfc      = (const float*)d_in[8];
  float* out = (float*)d_out;

  char* ws = (char*)d_ws;
  __bf16* ws_wq  = (__bf16*)(ws);
  __bf16* ws_wk  = (__bf16*)(ws + 32768);
  __bf16* ws_wfc = (__bf16*)(ws + 65536);

  hipLaunchKernelGGL(k0_weights, dim3(512), dim3(256), 0, stream,
                     Wq, Wk, Wfc, ws_wq, ws_wk, ws_wfc, out);
  hipLaunchKernelGGL(k_fused, dim3(kB, 2), dim3(256), 0, stream,
                     features, sidx, gamma, beta, ws_wq, ws_wk, Wv1, Wv2, ws_wfc, out);
}

// Round 6
// 135.899 us; speedup vs baseline: 1.1640x; 1.0021x over previous
//
#include <hip/hip_runtime.h>

typedef __bf16 v8bf __attribute__((ext_vector_type(8)));
typedef __bf16 v4bf __attribute__((ext_vector_type(4)));
typedef __bf16 v2bf __attribute__((ext_vector_type(2)));
typedef float  v4f  __attribute__((ext_vector_type(4)));
typedef float  v2f  __attribute__((ext_vector_type(2)));
typedef unsigned long long u64;

namespace {

constexpr int kB = 512, kM = 4096, kH = 8;

// ws layout (bytes): wq 32KB @ 0, wk 32KB @ 32768, wfc 64KB @ 65536
// Tile swizzle: element (r, c) of a row-major [R x C] matrix lives at
//   tile = (r>>4)*(C/32) + (c>>5);  addr = tile*512 + (r&15)*32 + (c&31)

// ---------------- K0: weight casts + swizzle + zero-init of fc out region ----------------
__global__ __launch_bounds__(256) void k0_weights(
    const float* __restrict__ Wq, const float* __restrict__ Wk,
    const float* __restrict__ Wfc,
    __bf16* __restrict__ wq, __bf16* __restrict__ wk, __bf16* __restrict__ wfc,
    float* __restrict__ out) {
  int i = blockIdx.x * 256 + threadIdx.x;
  float4 z = make_float4(0.f, 0.f, 0.f, 0.f);
#pragma unroll
  for (int j = 0; j < 4; ++j) reinterpret_cast<float4*>(out)[i + j * 131072] = z;
  if (i < 16384) {
    int e = i >> 6, k = i & 63;
    int dst = ((e >> 4) * 2 + (k >> 5)) * 512 + (e & 15) * 32 + (k & 31);
    wq[dst] = (__bf16)(Wq[i] * 0.015625f);
  } else if (i < 32768) {
    int j = i - 16384;
    int e = j >> 6, k = j & 63;
    int dst = ((e >> 4) * 2 + (k >> 5)) * 512 + (e & 15) * 32 + (k & 31);
    wk[dst] = (__bf16)Wk[j];
  } else if (i < 65536) {
    int j = i - 32768;
    int o = j >> 9, f = j & 511;
    int dst = ((o >> 4) * 16 + (f >> 5)) * 512 + (o & 15) * 32 + (f & 31);
    wfc[dst] = (__bf16)Wfc[j];
  }
}

// ---------------- K1: fused kernel, 4 heads per block, 2 blocks per b ----------------
// grid (512, 2), 256 threads, LDS 40448 B -> 4 blocks/CU, one scheduling round.
// All attention-side reshapes (scores->softmax->PV->fc) are register-resident via
// swapped MFMAs + in-wave shfl transposes; LDS is only used for cross-wave data
// (s_feat gather source, s_qin, s_kf conv input, s_K, s_vT). 3 barriers/head.
__global__ __launch_bounds__(256, 4) void k_fused(
    const float* __restrict__ feat, const int* __restrict__ sidx,
    const float* __restrict__ gamma, const float* __restrict__ beta,
    const __bf16* __restrict__ wq, const __bf16* __restrict__ wk,
    const float* __restrict__ Wv1, const float* __restrict__ Wv2,
    const __bf16* __restrict__ wfc, float* __restrict__ out) {
  __shared__ __align__(16) __bf16 smem[19968];  // 39,936 B
  __shared__ float red[4];
  __bf16* s_feat = smem;           // 4096   raw features bf16 (gather source, all heads)
  __bf16* s_qin  = smem + 4096;    // 4096   LN output, tile-swizzled (all heads)
  __bf16* s_kf   = smem + 8192;    // 64x72  gathered kf (conv input; pads zeroed once)
  __bf16* s_K    = smem + 12800;   // 64x40  K[n][d]
  __bf16* s_vT   = smem + 15360;   // 64x72  v^T [s][n]

  const int b = blockIdx.x, half = blockIdx.y, h0 = 4 * half;
  const int t = threadIdx.x, w = t >> 6, lane = t & 63;
  const int quad = lane >> 4, l16 = lane & 15;
  const int myrow = 16 * w + l16;  // kf/K/q/o row owned by this lane

  // ---- LN phase (+ prefetch first head's gather indices, vectorized) ----
  const float4* frow4 = reinterpret_cast<const float4*>(feat + (size_t)b * kM);
  const float4* g4  = reinterpret_cast<const float4*>(gamma);
  const float4* be4 = reinterpret_cast<const float4*>(beta);
  float4 xs[4];
  float s = 0.f;
#pragma unroll
  for (int j = 0; j < 4; ++j) {
    xs[j] = frow4[t + j * 256];
    s += xs[j].x + xs[j].y + xs[j].z + xs[j].w;
  }
  int4 idxc[4], idxn[4];
  {
    const int* ibase = sidx + (size_t)h0 * kM + myrow * 64 + 8 * quad;
#pragma unroll
    for (int p = 0; p < 4; ++p)
      idxc[p] = *(const int4*)(ibase + 32 * (p >> 1) + 4 * (p & 1));
  }
#pragma unroll
  for (int o = 32; o > 0; o >>= 1) s += __shfl_xor(s, o);
  if (lane == 0) red[w] = s;
  __syncthreads();
  const float mu = (red[0] + red[1] + red[2] + red[3]) * (1.f / kM);
  float var_p = 0.f;
#pragma unroll
  for (int j = 0; j < 4; ++j) {
    float d0 = xs[j].x - mu, d1 = xs[j].y - mu, d2 = xs[j].z - mu, d3 = xs[j].w - mu;
    var_p += d0 * d0 + d1 * d1 + d2 * d2 + d3 * d3;
  }
#pragma unroll
  for (int o = 32; o > 0; o >>= 1) var_p += __shfl_xor(var_p, o);
  __syncthreads();
  if (lane == 0) red[w] = var_p;
  __syncthreads();
  const float var  = (red[0] + red[1] + red[2] + red[3]) * (1.f / kM);
  const float rstd = rsqrtf(var + 1e-5f);
#pragma unroll
  for (int j = 0; j < 4; ++j) {
    const int i4 = t + j * 256;
    float4 g = g4[i4], bt = be4[i4];
    v4bf fb, qb;
    fb[0] = (__bf16)xs[j].x; fb[1] = (__bf16)xs[j].y;
    fb[2] = (__bf16)xs[j].z; fb[3] = (__bf16)xs[j].w;
    qb[0] = (__bf16)((xs[j].x - mu) * rstd * g.x + bt.x);
    qb[1] = (__bf16)((xs[j].y - mu) * rstd * g.y + bt.y);
    qb[2] = (__bf16)((xs[j].z - mu) * rstd * g.z + bt.z);
    qb[3] = (__bf16)((xs[j].w - mu) * rstd * g.w + bt.w);
    *(v4bf*)(s_feat + 4 * i4) = fb;
    const int n = i4 >> 4, k = 4 * (t & 15);
    const int dst = ((n >> 4) * 2 + (k >> 5)) * 512 + (n & 15) * 32 + (k & 31);
    *(v4bf*)(s_qin + dst) = qb;
  }
  // conv pad cols 64..71: zero ONCE (nothing clobbers them anymore)
  if (t < 64) { v8bf z = {}; *(v8bf*)(s_kf + t * 72 + 64) = z; }
  __syncthreads();  // bar0: s_feat, s_qin, pads ready

  v4f acc[4] = {{0.f, 0.f, 0.f, 0.f}, {0.f, 0.f, 0.f, 0.f},
                {0.f, 0.f, 0.f, 0.f}, {0.f, 0.f, 0.f, 0.f}};  // fc partial (this half)

  for (int it = 0; it < 4; ++it) {
    const int h = h0 + it;

    // ---- q-GEMM, operand-swapped: q register-resident as aq (row myrow, octet quad)
    v8bf aq;
    {
      v4f dq0 = {0.f, 0.f, 0.f, 0.f}, dq1 = {0.f, 0.f, 0.f, 0.f};
#pragma unroll
      for (int kt = 0; kt < 2; ++kt) {
        v8bf a  = *(const v8bf*)(s_qin + (2 * w + kt) * 512 + l16 * 32 + 8 * quad);
        v8bf b0 = *(const v8bf*)(wq + (size_t)(4 * h + kt) * 512 + l16 * 32 + 8 * quad);
        v8bf b1 = *(const v8bf*)(wq + (size_t)(4 * h + 2 + kt) * 512 + l16 * 32 + 8 * quad);
        dq0 = __builtin_amdgcn_mfma_f32_16x16x32_bf16(b0, a, dq0, 0, 0, 0);
        dq1 = __builtin_amdgcn_mfma_f32_16x16x32_bf16(b1, a, dq1, 0, 0, 0);
      }
      v4bf p0, p1;
#pragma unroll
      for (int r = 0; r < 4; ++r) { p0[r] = (__bf16)dq0[r]; p1[r] = (__bf16)dq1[r]; }
      const u64 P0 = __builtin_bit_cast(u64, p0), P1 = __builtin_bit_cast(u64, p1);
      const int qs = 16 * (2 * (quad & 1));
      u64 s0p0 = __shfl(P0, l16 + qs),      s0p1 = __shfl(P1, l16 + qs);
      u64 s1p0 = __shfl(P0, l16 + qs + 16), s1p1 = __shfl(P1, l16 + qs + 16);
      v4bf lo = __builtin_bit_cast(v4bf, (quad >> 1) ? s0p1 : s0p0);
      v4bf hi = __builtin_bit_cast(v4bf, (quad >> 1) ? s1p1 : s1p0);
#pragma unroll
      for (int r = 0; r < 4; ++r) { aq[r] = lo[r]; aq[4 + r] = hi[r]; }
    }

    // ---- prefetch next head's gather indices (4 x int4)
    if (it < 3) {
      const int* ibase = sidx + (size_t)(h + 1) * kM + myrow * 64 + 8 * quad;
#pragma unroll
      for (int p = 0; p < 4; ++p)
        idxn[p] = *(const int4*)(ibase + 32 * (p >> 1) + 4 * (p & 1));
    }

    // ---- gather straight into K-GEMM kf fragments (wave-private rows myrow)
    v8bf a0, a1;
    a0[0] = s_feat[idxc[0].x]; a0[1] = s_feat[idxc[0].y];
    a0[2] = s_feat[idxc[0].z]; a0[3] = s_feat[idxc[0].w];
    a0[4] = s_feat[idxc[1].x]; a0[5] = s_feat[idxc[1].y];
    a0[6] = s_feat[idxc[1].z]; a0[7] = s_feat[idxc[1].w];
    a1[0] = s_feat[idxc[2].x]; a1[1] = s_feat[idxc[2].y];
    a1[2] = s_feat[idxc[2].z]; a1[3] = s_feat[idxc[2].w];
    a1[4] = s_feat[idxc[3].x]; a1[5] = s_feat[idxc[3].y];
    a1[6] = s_feat[idxc[3].z]; a1[7] = s_feat[idxc[3].w];
    *(v8bf*)(s_kf + myrow * 72 + 8 * quad)      = a0;
    *(v8bf*)(s_kf + myrow * 72 + 32 + 8 * quad) = a1;

    // ---- K-GEMM, operand-swapped: lane holds K[myrow][4quad..+3] & [16+4quad..+3]
    {
      v4f dk0 = {0.f, 0.f, 0.f, 0.f}, dk1 = {0.f, 0.f, 0.f, 0.f};
      v8bf b00 = *(const v8bf*)(wk + (size_t)(4 * h + 0) * 512 + l16 * 32 + 8 * quad);
      v8bf b10 = *(const v8bf*)(wk + (size_t)(4 * h + 2) * 512 + l16 * 32 + 8 * quad);
      dk0 = __builtin_amdgcn_mfma_f32_16x16x32_bf16(b00, a0, dk0, 0, 0, 0);
      dk1 = __builtin_amdgcn_mfma_f32_16x16x32_bf16(b10, a0, dk1, 0, 0, 0);
      v8bf b01 = *(const v8bf*)(wk + (size_t)(4 * h + 1) * 512 + l16 * 32 + 8 * quad);
      v8bf b11 = *(const v8bf*)(wk + (size_t)(4 * h + 3) * 512 + l16 * 32 + 8 * quad);
      dk0 = __builtin_amdgcn_mfma_f32_16x16x32_bf16(b01, a1, dk0, 0, 0, 0);
      dk1 = __builtin_amdgcn_mfma_f32_16x16x32_bf16(b11, a1, dk1, 0, 0, 0);
      v4bf p0, p1;
#pragma unroll
      for (int r = 0; r < 4; ++r) { p0[r] = (__bf16)dk0[r]; p1[r] = (__bf16)dk1[r]; }
      *(v4bf*)(s_K + myrow * 40 + 4 * quad)      = p0;
      *(v4bf*)(s_K + myrow * 40 + 16 + 4 * quad) = p1;
    }
    __syncthreads();  // bar A: s_kf (all rows) + s_K ready

    // ---- windowed conv + relu + residual, float2-packed, vT[s][n]
    {
      const int n = lane, p0c = w * 16;
      float w1[4][3], w2[4];
#pragma unroll
      for (int d = 0; d < 4; ++d) {
#pragma unroll
        for (int c = 0; c < 3; ++c) w1[d][c] = Wv1[(h * 4 + d) * 3 + c];
        w2[d] = Wv2[h * 4 + d];
      }
      v8bf xa = *(const v8bf*)(s_kf + n * 72 + p0c);
      v8bf xb = *(const v8bf*)(s_kf + n * 72 + p0c + 8);
      v2bf xc = *(const v2bf*)(s_kf + n * 72 + p0c + 16);  // pad cols zeroed once
      v2f x2[10];
#pragma unroll
      for (int j = 0; j < 8; ++j) { x2[j][0] = (float)xa[j]; x2[j][1] = (float)xb[j]; }
      x2[8][0] = (float)xb[0]; x2[8][1] = (float)xc[0];
      x2[9][0] = (float)xb[1]; x2[9][1] = (float)xc[1];
      const v2f z2 = {0.f, 0.f};
#pragma unroll
      for (int pp = 0; pp < 8; ++pp) {
        v2f a2 = x2[pp];
#pragma unroll
        for (int d = 0; d < 4; ++d) {
          v2f v1 = x2[pp] * w1[d][0] + x2[pp + 1] * w1[d][1] + x2[pp + 2] * w1[d][2];
          v1 = __builtin_elementwise_max(v1, z2);
          a2 = a2 + v1 * w2[d];
        }
        s_vT[(p0c + pp) * 72 + n]     = (__bf16)a2[0];
        s_vT[(p0c + pp + 8) * 72 + n] = (__bf16)a2[1];
      }
    }
    __syncthreads();  // bar B: s_vT ready

    // ---- scores, swapped: sc[nt][r] = scores[qi=myrow][n=16nt+4quad+r] (row-local!)
    v4f sc[4];
#pragma unroll
    for (int nt = 0; nt < 4; ++nt) {
      v4f zz = {0.f, 0.f, 0.f, 0.f};
      v8bf bbK = *(const v8bf*)(s_K + (16 * nt + l16) * 40 + 8 * quad);
      sc[nt] = __builtin_amdgcn_mfma_f32_16x16x32_bf16(bbK, aq, zz, 0, 0, 0);
    }

    // ---- softmax fully in registers: 15-op local max + 2 shfl_xor, same for sum
    float mx = sc[0][0];
#pragma unroll
    for (int nt = 0; nt < 4; ++nt)
#pragma unroll
      for (int r = 0; r < 4; ++r) mx = fmaxf(mx, sc[nt][r]);
    mx = fmaxf(mx, __shfl_xor(mx, 16));
    mx = fmaxf(mx, __shfl_xor(mx, 32));
    float ssum = 0.f;
#pragma unroll
    for (int nt = 0; nt < 4; ++nt)
#pragma unroll
      for (int r = 0; r < 4; ++r) {
        float e = __expf(sc[nt][r] - mx);
        sc[nt][r] = e; ssum += e;
      }
    ssum += __shfl_xor(ssum, 16);
    ssum += __shfl_xor(ssum, 32);
    const float inv = 1.0f / ssum;
#pragma unroll
    for (int nt = 0; nt < 4; ++nt) sc[nt] *= inv;

    // ---- attn output: f32, 4x v4f stores at row myrow, cols 16nt+4quad..+3
    float* attn_out = out + (size_t)kB * kM + ((size_t)(b * kH + h)) * 4096;
#pragma unroll
    for (int nt = 0; nt < 4; ++nt)
      *(v4f*)(attn_out + myrow * 64 + 16 * nt + 4 * quad) = sc[nt];

    // ---- pack attn to bf16 (row-local), build PV A-fragments by shfl transpose
    v4bf P[4];
#pragma unroll
    for (int nt = 0; nt < 4; ++nt)
#pragma unroll
      for (int r = 0; r < 4; ++r) P[nt][r] = (__bf16)sc[nt][r];

    v4f dOT[4] = {{0.f, 0.f, 0.f, 0.f}, {0.f, 0.f, 0.f, 0.f},
                  {0.f, 0.f, 0.f, 0.f}, {0.f, 0.f, 0.f, 0.f}};
    const int src0 = l16 + 16 * (2 * (quad & 1));
#pragma unroll
    for (int kt = 0; kt < 2; ++kt) {
      const u64 pA = __builtin_bit_cast(u64, P[2 * kt]);
      const u64 pB = __builtin_bit_cast(u64, P[2 * kt + 1]);
      u64 A0 = __shfl(pA, src0), A1 = __shfl(pA, src0 + 16);
      u64 B0 = __shfl(pB, src0), B1 = __shfl(pB, src0 + 16);
      v4bf lo = __builtin_bit_cast(v4bf, (quad >> 1) ? B0 : A0);
      v4bf hi = __builtin_bit_cast(v4bf, (quad >> 1) ? B1 : A1);
      v8bf a_pv;
#pragma unroll
      for (int r = 0; r < 4; ++r) { a_pv[r] = lo[r]; a_pv[4 + r] = hi[r]; }
      // PV swapped: dOT[st] holds o[qi=myrow][s=16st+4quad+r] (row-local)
#pragma unroll
      for (int st = 0; st < 4; ++st) {
        v8bf bb = *(const v8bf*)(s_vT + (16 * st + l16) * 72 + 32 * kt + 8 * quad);
        dOT[st] = __builtin_amdgcn_mfma_f32_16x16x32_bf16(bb, a_pv, dOT[st], 0, 0, 0);
      }
    }
    __syncthreads();  // bar C: all cross-wave s_K/s_vT/s_kf reads of this head done

    // ---- fc partial (pure reg + global): rebuild o A-fragment by the same transpose
    {
      v4bf Q[4];
#pragma unroll
      for (int st = 0; st < 4; ++st)
#pragma unroll
        for (int r = 0; r < 4; ++r) Q[st][r] = (__bf16)dOT[st][r];
#pragma unroll
      for (int kt = 0; kt < 2; ++kt) {
        const u64 qA = __builtin_bit_cast(u64, Q[2 * kt]);
        const u64 qB = __builtin_bit_cast(u64, Q[2 * kt + 1]);
        u64 A0 = __shfl(qA, src0), A1 = __shfl(qA, src0 + 16);
        u64 B0 = __shfl(qB, src0), B1 = __shfl(qB, src0 + 16);
        v4bf lo = __builtin_bit_cast(v4bf, (quad >> 1) ? B0 : A0);
        v4bf hi = __builtin_bit_cast(v4bf, (quad >> 1) ? B1 : A1);
        v8bf a_fc;
#pragma unroll
        for (int r = 0; r < 4; ++r) { a_fc[r] = lo[r]; a_fc[4 + r] = hi[r]; }
#pragma unroll
        for (int nt = 0; nt < 4; ++nt) {
          v8bf bb = *(const v8bf*)(wfc + (size_t)(nt * 16 + h * 2 + kt) * 512 + l16 * 32 + 8 * quad);
          acc[nt] = __builtin_amdgcn_mfma_f32_16x16x32_bf16(a_fc, bb, acc[nt], 0, 0, 0);
        }
      }
    }

    if (it < 3) {
#pragma unroll
      for (int p = 0; p < 4; ++p) idxc[p] = idxn[p];
    }
  }

  // ---- combine fc partials across the two half-blocks via atomicAdd (out pre-zeroed by k0)
  float* orow = out + (size_t)b * kM;
#pragma unroll
  for (int nt = 0; nt < 4; ++nt)
#pragma unroll
    for (int r = 0; r < 4; ++r)
      atomicAdd(&orow[(16 * w + 4 * quad + r) * 64 + 16 * nt + l16], acc[nt][r]);
}

}  // namespace

extern "C" void kernel_launch(void* const* d_in, const int* in_sizes, int n_in,
                              void* d_out, int out_size, void* d_ws, size_t ws_size,
                              hipStream_t stream) {
  (void)in_sizes; (void)n_in; (void)out_size; (void)ws_size;
  const float* features = (const float*)d_in[0];
  const int*   sidx     = (const int*)d_in[1];
  const float* gamma    = (const float*)d_in[2];
  const float* beta     = (const float*)d_in[3];
  const float* Wq       = (const float*)d_in[4];
  const float* Wk       = (const float*)d_in[5];
  const float* Wv1      = (const float*)d_in[6];
  const float* Wv2      = (const float*)d_in[7];
  const float* Wfc      = (const float*)d_in[8];
  float* out = (float*)d_out;

  char* ws = (char*)d_ws;
  __bf16* ws_wq  = (__bf16*)(ws);
  __bf16* ws_wk  = (__bf16*)(ws + 32768);
  __bf16* ws_wfc = (__bf16*)(ws + 65536);

  hipLaunchKernelGGL(k0_weights, dim3(512), dim3(256), 0, stream,
                     Wq, Wk, Wfc, ws_wq, ws_wk, ws_wfc, out);
  hipLaunchKernelGGL(k_fused, dim3(kB, 2), dim3(256), 0, stream,
                     features, sidx, gamma, beta, ws_wq, ws_wk, Wv1, Wv2, ws_wfc, out);
}

// Round 7
// 130.934 us; speedup vs baseline: 1.2081x; 1.0379x over previous
//
#include <hip/hip_runtime.h>

typedef __bf16 v8bf __attribute__((ext_vector_type(8)));
typedef __bf16 v4bf __attribute__((ext_vector_type(4)));
typedef __bf16 v2bf __attribute__((ext_vector_type(2)));
typedef float  v4f  __attribute__((ext_vector_type(4)));
typedef float  v2f  __attribute__((ext_vector_type(2)));
typedef unsigned long long u64;

namespace {

constexpr int kB = 512, kM = 4096, kH = 8;

// ws layout (bytes): wq 32KB @ 0, wk 32KB @ 32768, wfc 64KB @ 65536
// Tile swizzle: element (r, c) of a row-major [R x C] matrix lives at
//   tile = (r>>4)*(C/32) + (c>>5);  addr = tile*512 + (r&15)*32 + (c&31)

// ---------------- K0: weight casts + swizzle + zero-init of fc out region ----------------
__global__ __launch_bounds__(256) void k0_weights(
    const float* __restrict__ Wq, const float* __restrict__ Wk,
    const float* __restrict__ Wfc,
    __bf16* __restrict__ wq, __bf16* __restrict__ wk, __bf16* __restrict__ wfc,
    float* __restrict__ out) {
  int i = blockIdx.x * 256 + threadIdx.x;
  float4 z = make_float4(0.f, 0.f, 0.f, 0.f);
#pragma unroll
  for (int j = 0; j < 4; ++j) reinterpret_cast<float4*>(out)[i + j * 131072] = z;
  if (i < 16384) {
    int e = i >> 6, k = i & 63;
    int dst = ((e >> 4) * 2 + (k >> 5)) * 512 + (e & 15) * 32 + (k & 31);
    wq[dst] = (__bf16)(Wq[i] * 0.015625f);
  } else if (i < 32768) {
    int j = i - 16384;
    int e = j >> 6, k = j & 63;
    int dst = ((e >> 4) * 2 + (k >> 5)) * 512 + (e & 15) * 32 + (k & 31);
    wk[dst] = (__bf16)Wk[j];
  } else if (i < 65536) {
    int j = i - 32768;
    int o = j >> 9, f = j & 511;
    int dst = ((o >> 4) * 16 + (f >> 5)) * 512 + (o & 15) * 32 + (f & 31);
    wfc[dst] = (__bf16)Wfc[j];
  }
}

// ---------------- K1: fused kernel, 4 heads per block, 2 blocks per b ----------------
// grid (512, 2), 256 threads, LDS 36.9 KB -> 4 blocks/CU, one scheduling round.
// qGEMM hoisted to prologue (head-invariant A); s_K double-buffered -> 2 barriers/head;
// gather prefetched one head ahead; fc overlapped into the next head's pre-barrier slot.
__global__ __launch_bounds__(256, 4) void k_fused(
    const float* __restrict__ feat, const int* __restrict__ sidx,
    const float* __restrict__ gamma, const float* __restrict__ beta,
    const __bf16* __restrict__ wq, const __bf16* __restrict__ wk,
    const float* __restrict__ Wv1, const float* __restrict__ Wv2,
    const __bf16* __restrict__ wfc, float* __restrict__ out) {
  __shared__ __align__(16) __bf16 smem[18432];  // 36,864 B
  __shared__ float red[4];
  __bf16* s_feat = smem;            // 4096   raw features bf16 (gather source, all heads)
  __bf16* s_kf   = smem + 4096;     // 64x72  gathered kf (conv input; pads zeroed once)
  __bf16* s_K0   = smem + 8704;     // 64x40  K[n][d], buffer 0
  __bf16* s_K1   = smem + 11264;    // 64x40  K[n][d], buffer 1
  __bf16* s_vT   = smem + 13824;    // 64x72  v^T [s][n]
  __bf16* s_qin  = smem + 4096;     // alias over s_kf: LN output, dead after prologue

  const int b = blockIdx.x, half = blockIdx.y, h0 = 4 * half;
  const int t = threadIdx.x, w = t >> 6, lane = t & 63;
  const int quad = lane >> 4, l16 = lane & 15;
  const int myrow = 16 * w + l16;  // kf/K/q/o row owned by this lane

  // ---- LN phase (+ prefetch first head's gather indices) ----
  const float4* frow4 = reinterpret_cast<const float4*>(feat + (size_t)b * kM);
  const float4* g4  = reinterpret_cast<const float4*>(gamma);
  const float4* be4 = reinterpret_cast<const float4*>(beta);
  float4 xs[4];
  float s = 0.f;
#pragma unroll
  for (int j = 0; j < 4; ++j) {
    xs[j] = frow4[t + j * 256];
    s += xs[j].x + xs[j].y + xs[j].z + xs[j].w;
  }
  int4 idxc[4];
  {
    const int* ibase = sidx + (size_t)h0 * kM + myrow * 64 + 8 * quad;
#pragma unroll
    for (int p = 0; p < 4; ++p)
      idxc[p] = *(const int4*)(ibase + 32 * (p >> 1) + 4 * (p & 1));
  }
#pragma unroll
  for (int o = 32; o > 0; o >>= 1) s += __shfl_xor(s, o);
  if (lane == 0) red[w] = s;
  __syncthreads();
  const float mu = (red[0] + red[1] + red[2] + red[3]) * (1.f / kM);
  float var_p = 0.f;
#pragma unroll
  for (int j = 0; j < 4; ++j) {
    float d0 = xs[j].x - mu, d1 = xs[j].y - mu, d2 = xs[j].z - mu, d3 = xs[j].w - mu;
    var_p += d0 * d0 + d1 * d1 + d2 * d2 + d3 * d3;
  }
#pragma unroll
  for (int o = 32; o > 0; o >>= 1) var_p += __shfl_xor(var_p, o);
  __syncthreads();
  if (lane == 0) red[w] = var_p;
  __syncthreads();
  const float var  = (red[0] + red[1] + red[2] + red[3]) * (1.f / kM);
  const float rstd = rsqrtf(var + 1e-5f);
#pragma unroll
  for (int j = 0; j < 4; ++j) {
    const int i4 = t + j * 256;
    float4 g = g4[i4], bt = be4[i4];
    v4bf fb, qb;
    fb[0] = (__bf16)xs[j].x; fb[1] = (__bf16)xs[j].y;
    fb[2] = (__bf16)xs[j].z; fb[3] = (__bf16)xs[j].w;
    qb[0] = (__bf16)((xs[j].x - mu) * rstd * g.x + bt.x);
    qb[1] = (__bf16)((xs[j].y - mu) * rstd * g.y + bt.y);
    qb[2] = (__bf16)((xs[j].z - mu) * rstd * g.z + bt.z);
    qb[3] = (__bf16)((xs[j].w - mu) * rstd * g.w + bt.w);
    *(v4bf*)(s_feat + 4 * i4) = fb;
    const int n = i4 >> 4, k = 4 * (t & 15);
    const int dst = ((n >> 4) * 2 + (k >> 5)) * 512 + (n & 15) * 32 + (k & 31);
    *(v4bf*)(s_qin + dst) = qb;
  }
  __syncthreads();  // bar0: s_feat + s_qin ready

  // ---- prologue qGEMM for ALL 4 heads (A-operand is head-invariant) ----
  const int qs = 16 * (2 * (quad & 1));
  v8bf aq[4];
  {
    v8bf aA0 = *(const v8bf*)(s_qin + (2 * w + 0) * 512 + l16 * 32 + 8 * quad);
    v8bf aA1 = *(const v8bf*)(s_qin + (2 * w + 1) * 512 + l16 * 32 + 8 * quad);
#pragma unroll
    for (int itq = 0; itq < 4; ++itq) {
      const int h = h0 + itq;
      v4f dq0 = {0.f, 0.f, 0.f, 0.f}, dq1 = {0.f, 0.f, 0.f, 0.f};
      v8bf b00 = *(const v8bf*)(wq + (size_t)(4 * h + 0) * 512 + l16 * 32 + 8 * quad);
      v8bf b01 = *(const v8bf*)(wq + (size_t)(4 * h + 1) * 512 + l16 * 32 + 8 * quad);
      v8bf b10 = *(const v8bf*)(wq + (size_t)(4 * h + 2) * 512 + l16 * 32 + 8 * quad);
      v8bf b11 = *(const v8bf*)(wq + (size_t)(4 * h + 3) * 512 + l16 * 32 + 8 * quad);
      dq0 = __builtin_amdgcn_mfma_f32_16x16x32_bf16(b00, aA0, dq0, 0, 0, 0);
      dq0 = __builtin_amdgcn_mfma_f32_16x16x32_bf16(b01, aA1, dq0, 0, 0, 0);
      dq1 = __builtin_amdgcn_mfma_f32_16x16x32_bf16(b10, aA0, dq1, 0, 0, 0);
      dq1 = __builtin_amdgcn_mfma_f32_16x16x32_bf16(b11, aA1, dq1, 0, 0, 0);
      v4bf p0, p1;
#pragma unroll
      for (int r = 0; r < 4; ++r) { p0[r] = (__bf16)dq0[r]; p1[r] = (__bf16)dq1[r]; }
      const u64 P0 = __builtin_bit_cast(u64, p0), P1 = __builtin_bit_cast(u64, p1);
      u64 s0p0 = __shfl(P0, l16 + qs),      s0p1 = __shfl(P1, l16 + qs);
      u64 s1p0 = __shfl(P0, l16 + qs + 16), s1p1 = __shfl(P1, l16 + qs + 16);
      v4bf lo = __builtin_bit_cast(v4bf, (quad >> 1) ? s0p1 : s0p0);
      v4bf hi = __builtin_bit_cast(v4bf, (quad >> 1) ? s1p1 : s1p0);
#pragma unroll
      for (int r = 0; r < 4; ++r) { aq[itq][r] = lo[r]; aq[itq][4 + r] = hi[r]; }
    }
  }

  // ---- gather head 0 into registers (s_feat ready since bar0)
  v8bf g0, g1;
  g0[0] = s_feat[idxc[0].x]; g0[1] = s_feat[idxc[0].y];
  g0[2] = s_feat[idxc[0].z]; g0[3] = s_feat[idxc[0].w];
  g0[4] = s_feat[idxc[1].x]; g0[5] = s_feat[idxc[1].y];
  g0[6] = s_feat[idxc[1].z]; g0[7] = s_feat[idxc[1].w];
  g1[0] = s_feat[idxc[2].x]; g1[1] = s_feat[idxc[2].y];
  g1[2] = s_feat[idxc[2].z]; g1[3] = s_feat[idxc[2].w];
  g1[4] = s_feat[idxc[3].x]; g1[5] = s_feat[idxc[3].y];
  g1[6] = s_feat[idxc[3].z]; g1[7] = s_feat[idxc[3].w];
  __syncthreads();  // bar0b: all s_qin reads done; s_kf region reusable

  // conv pad cols 64..71: zero once (region was s_qin-aliased, so after bar0b)
  if (t < 64) { v8bf z = {}; *(v8bf*)(s_kf + t * 72 + 64) = z; }

  v4f acc[4] = {{0.f, 0.f, 0.f, 0.f}, {0.f, 0.f, 0.f, 0.f},
                {0.f, 0.f, 0.f, 0.f}, {0.f, 0.f, 0.f, 0.f}};  // fc partial (this half)
  v4bf Qprev[4];

  for (int it = 0; it < 4; ++it) {
    const int h = h0 + it;
    __bf16* s_K = (it & 1) ? s_K1 : s_K0;

    // ---- dump gather regs to s_kf (conv input), K-GEMM from regs
    *(v8bf*)(s_kf + myrow * 72 + 8 * quad)      = g0;
    *(v8bf*)(s_kf + myrow * 72 + 32 + 8 * quad) = g1;
    {
      v4f dk0 = {0.f, 0.f, 0.f, 0.f}, dk1 = {0.f, 0.f, 0.f, 0.f};
      v8bf b00 = *(const v8bf*)(wk + (size_t)(4 * h + 0) * 512 + l16 * 32 + 8 * quad);
      v8bf b10 = *(const v8bf*)(wk + (size_t)(4 * h + 2) * 512 + l16 * 32 + 8 * quad);
      dk0 = __builtin_amdgcn_mfma_f32_16x16x32_bf16(b00, g0, dk0, 0, 0, 0);
      dk1 = __builtin_amdgcn_mfma_f32_16x16x32_bf16(b10, g0, dk1, 0, 0, 0);
      v8bf b01 = *(const v8bf*)(wk + (size_t)(4 * h + 1) * 512 + l16 * 32 + 8 * quad);
      v8bf b11 = *(const v8bf*)(wk + (size_t)(4 * h + 3) * 512 + l16 * 32 + 8 * quad);
      dk0 = __builtin_amdgcn_mfma_f32_16x16x32_bf16(b01, g1, dk0, 0, 0, 0);
      dk1 = __builtin_amdgcn_mfma_f32_16x16x32_bf16(b11, g1, dk1, 0, 0, 0);
      v4bf p0, p1;
#pragma unroll
      for (int r = 0; r < 4; ++r) { p0[r] = (__bf16)dk0[r]; p1[r] = (__bf16)dk1[r]; }
      *(v4bf*)(s_K + myrow * 40 + 4 * quad)      = p0;
      *(v4bf*)(s_K + myrow * 40 + 16 + 4 * quad) = p1;
    }

    // ---- fc for previous head (registers + global wfc only): overlaps staging
    if (it > 0) {
      const int hp = h - 1;
#pragma unroll
      for (int kt = 0; kt < 2; ++kt) {
        const u64 qA = __builtin_bit_cast(u64, Qprev[2 * kt]);
        const u64 qB = __builtin_bit_cast(u64, Qprev[2 * kt + 1]);
        u64 A0 = __shfl(qA, l16 + qs), A1 = __shfl(qA, l16 + qs + 16);
        u64 B0 = __shfl(qB, l16 + qs), B1 = __shfl(qB, l16 + qs + 16);
        v4bf lo = __builtin_bit_cast(v4bf, (quad >> 1) ? B0 : A0);
        v4bf hi = __builtin_bit_cast(v4bf, (quad >> 1) ? B1 : A1);
        v8bf a_fc;
#pragma unroll
        for (int r = 0; r < 4; ++r) { a_fc[r] = lo[r]; a_fc[4 + r] = hi[r]; }
#pragma unroll
        for (int nt = 0; nt < 4; ++nt) {
          v8bf bb = *(const v8bf*)(wfc + (size_t)(nt * 16 + hp * 2 + kt) * 512 + l16 * 32 + 8 * quad);
          acc[nt] = __builtin_amdgcn_mfma_f32_16x16x32_bf16(a_fc, bb, acc[nt], 0, 0, 0);
        }
      }
    }
    __syncthreads();  // bar1: s_kf + s_K[it&1] ready; prev head's PV/scores reads all done

    // ---- windowed conv + relu + residual, float2-packed, vT[s][n]
    // (+ prefetch next head's gather: idx loads hidden under conv VALU, ds_reads after)
    {
      int4 ixn[4];
      if (it < 3) {
        const int* ibase = sidx + (size_t)(h + 1) * kM + myrow * 64 + 8 * quad;
#pragma unroll
        for (int p = 0; p < 4; ++p)
          ixn[p] = *(const int4*)(ibase + 32 * (p >> 1) + 4 * (p & 1));
      }
      const int n = lane, p0c = w * 16;
      float w1[4][3], w2[4];
#pragma unroll
      for (int d = 0; d < 4; ++d) {
#pragma unroll
        for (int c = 0; c < 3; ++c) w1[d][c] = Wv1[(h * 4 + d) * 3 + c];
        w2[d] = Wv2[h * 4 + d];
      }
      v8bf xa = *(const v8bf*)(s_kf + n * 72 + p0c);
      v8bf xb = *(const v8bf*)(s_kf + n * 72 + p0c + 8);
      v2bf xc = *(const v2bf*)(s_kf + n * 72 + p0c + 16);  // pad cols zeroed once
      v2f x2[10];
#pragma unroll
      for (int j = 0; j < 8; ++j) { x2[j][0] = (float)xa[j]; x2[j][1] = (float)xb[j]; }
      x2[8][0] = (float)xb[0]; x2[8][1] = (float)xc[0];
      x2[9][0] = (float)xb[1]; x2[9][1] = (float)xc[1];
      const v2f z2 = {0.f, 0.f};
#pragma unroll
      for (int pp = 0; pp < 8; ++pp) {
        v2f a2 = x2[pp];
#pragma unroll
        for (int d = 0; d < 4; ++d) {
          v2f v1 = x2[pp] * w1[d][0] + x2[pp + 1] * w1[d][1] + x2[pp + 2] * w1[d][2];
          v1 = __builtin_elementwise_max(v1, z2);
          a2 = a2 + v1 * w2[d];
        }
        s_vT[(p0c + pp) * 72 + n]     = (__bf16)a2[0];
        s_vT[(p0c + pp + 8) * 72 + n] = (__bf16)a2[1];
      }
      if (it < 3) {  // gather next head now; consumed at next loop top (hidden by bar2+scores)
        g0[0] = s_feat[ixn[0].x]; g0[1] = s_feat[ixn[0].y];
        g0[2] = s_feat[ixn[0].z]; g0[3] = s_feat[ixn[0].w];
        g0[4] = s_feat[ixn[1].x]; g0[5] = s_feat[ixn[1].y];
        g0[6] = s_feat[ixn[1].z]; g0[7] = s_feat[ixn[1].w];
        g1[0] = s_feat[ixn[2].x]; g1[1] = s_feat[ixn[2].y];
        g1[2] = s_feat[ixn[2].z]; g1[3] = s_feat[ixn[2].w];
        g1[4] = s_feat[ixn[3].x]; g1[5] = s_feat[ixn[3].y];
        g1[6] = s_feat[ixn[3].z]; g1[7] = s_feat[ixn[3].w];
      }
    }
    __syncthreads();  // bar2: s_vT ready

    // ---- scores, swapped: sc[nt][r] = scores[qi=myrow][n=16nt+4quad+r] (row-local)
    v4f sc[4];
#pragma unroll
    for (int nt = 0; nt < 4; ++nt) {
      v4f zz = {0.f, 0.f, 0.f, 0.f};
      v8bf bbK = *(const v8bf*)(s_K + (16 * nt + l16) * 40 + 8 * quad);
      sc[nt] = __builtin_amdgcn_mfma_f32_16x16x32_bf16(bbK, aq[it], zz, 0, 0, 0);
    }

    // ---- softmax fully in registers
    float mx = sc[0][0];
#pragma unroll
    for (int nt = 0; nt < 4; ++nt)
#pragma unroll
      for (int r = 0; r < 4; ++r) mx = fmaxf(mx, sc[nt][r]);
    mx = fmaxf(mx, __shfl_xor(mx, 16));
    mx = fmaxf(mx, __shfl_xor(mx, 32));
    float ssum = 0.f;
#pragma unroll
    for (int nt = 0; nt < 4; ++nt)
#pragma unroll
      for (int r = 0; r < 4; ++r) {
        float e = __expf(sc[nt][r] - mx);
        sc[nt][r] = e; ssum += e;
      }
    ssum += __shfl_xor(ssum, 16);
    ssum += __shfl_xor(ssum, 32);
    const float inv = 1.0f / ssum;
#pragma unroll
    for (int nt = 0; nt < 4; ++nt) sc[nt] *= inv;

    // ---- attn output: f32, 4x v4f stores at row myrow
    float* attn_out = out + (size_t)kB * kM + ((size_t)(b * kH + h)) * 4096;
#pragma unroll
    for (int nt = 0; nt < 4; ++nt)
      *(v4f*)(attn_out + myrow * 64 + 16 * nt + 4 * quad) = sc[nt];

    // ---- pack attn to bf16, build PV A-fragments by shfl transpose, swapped PV
    v4bf P[4];
#pragma unroll
    for (int nt = 0; nt < 4; ++nt)
#pragma unroll
      for (int r = 0; r < 4; ++r) P[nt][r] = (__bf16)sc[nt][r];

    v4f dOT[4] = {{0.f, 0.f, 0.f, 0.f}, {0.f, 0.f, 0.f, 0.f},
                  {0.f, 0.f, 0.f, 0.f}, {0.f, 0.f, 0.f, 0.f}};
#pragma unroll
    for (int kt = 0; kt < 2; ++kt) {
      const u64 pA = __builtin_bit_cast(u64, P[2 * kt]);
      const u64 pB = __builtin_bit_cast(u64, P[2 * kt + 1]);
      u64 A0 = __shfl(pA, l16 + qs), A1 = __shfl(pA, l16 + qs + 16);
      u64 B0 = __shfl(pB, l16 + qs), B1 = __shfl(pB, l16 + qs + 16);
      v4bf lo = __builtin_bit_cast(v4bf, (quad >> 1) ? B0 : A0);
      v4bf hi = __builtin_bit_cast(v4bf, (quad >> 1) ? B1 : A1);
      v8bf a_pv;
#pragma unroll
      for (int r = 0; r < 4; ++r) { a_pv[r] = lo[r]; a_pv[4 + r] = hi[r]; }
#pragma unroll
      for (int st = 0; st < 4; ++st) {
        v8bf bb = *(const v8bf*)(s_vT + (16 * st + l16) * 72 + 32 * kt + 8 * quad);
        dOT[st] = __builtin_amdgcn_mfma_f32_16x16x32_bf16(bb, a_pv, dOT[st], 0, 0, 0);
      }
    }
    // pack o for fc (consumed next iteration / after loop)
#pragma unroll
    for (int st = 0; st < 4; ++st)
#pragma unroll
      for (int r = 0; r < 4; ++r) Qprev[st][r] = (__bf16)dOT[st][r];
    // no tail barrier: next head's writes touch s_kf (no readers here) and the
    // other s_K buffer; s_vT is fenced by next head's bar1.
  }

  // ---- fc for last head
  {
    const int hp = h0 + 3;
#pragma unroll
    for (int kt = 0; kt < 2; ++kt) {
      const u64 qA = __builtin_bit_cast(u64, Qprev[2 * kt]);
      const u64 qB = __builtin_bit_cast(u64, Qprev[2 * kt + 1]);
      u64 A0 = __shfl(qA, l16 + qs), A1 = __shfl(qA, l16 + qs + 16);
      u64 B0 = __shfl(qB, l16 + qs), B1 = __shfl(qB, l16 + qs + 16);
      v4bf lo = __builtin_bit_cast(v4bf, (quad >> 1) ? B0 : A0);
      v4bf hi = __builtin_bit_cast(v4bf, (quad >> 1) ? B1 : A1);
      v8bf a_fc;
#pragma unroll
      for (int r = 0; r < 4; ++r) { a_fc[r] = lo[r]; a_fc[4 + r] = hi[r]; }
#pragma unroll
      for (int nt = 0; nt < 4; ++nt) {
        v8bf bb = *(const v8bf*)(wfc + (size_t)(nt * 16 + hp * 2 + kt) * 512 + l16 * 32 + 8 * quad);
        acc[nt] = __builtin_amdgcn_mfma_f32_16x16x32_bf16(a_fc, bb, acc[nt], 0, 0, 0);
      }
    }
  }

  // ---- combine fc partials across the two half-blocks via atomicAdd (out pre-zeroed by k0)
  float* orow = out + (size_t)b * kM;
#pragma unroll
  for (int nt = 0; nt < 4; ++nt)
#pragma unroll
    for (int r = 0; r < 4; ++r)
      atomicAdd(&orow[(16 * w + 4 * quad + r) * 64 + 16 * nt + l16], acc[nt][r]);
}

}  // namespace

extern "C" void kernel_launch(void* const* d_in, const int* in_sizes, int n_in,
                              void* d_out, int out_size, void* d_ws, size_t ws_size,
                              hipStream_t stream) {
  (void)in_sizes; (void)n_in; (void)out_size; (void)ws_size;
  const float* features = (const float*)d_in[0];
  const int*   sidx     = (const int*)d_in[1];
  const float* gamma    = (const float*)d_in[2];
  const float* beta     = (const float*)d_in[3];
  const float* Wq       = (const float*)d_in[4];
  const float* Wk       = (const float*)d_in[5];
  const float* Wv1      = (const float*)d_in[6];
  const float* Wv2      = (const float*)d_in[7];
  const float* Wfc      = (const float*)d_in[8];
  float* out = (float*)d_out;

  char* ws = (char*)d_ws;
  __bf16* ws_wq  = (__bf16*)(ws);
  __bf16* ws_wk  = (__bf16*)(ws + 32768);
  __bf16* ws_wfc = (__bf16*)(ws + 65536);

  hipLaunchKernelGGL(k0_weights, dim3(512), dim3(256), 0, stream,
                     Wq, Wk, Wfc, ws_wq, ws_wk, ws_wfc, out);
  hipLaunchKernelGGL(k_fused, dim3(kB, 2), dim3(256), 0, stream,
                     features, sidx, gamma, beta, ws_wq, ws_wk, Wv1, Wv2, ws_wfc, out);
}